// Round 1
// baseline (686.261 us; speedup 1.0000x reference)
//
#include <hip/hip_runtime.h>

typedef __attribute__((ext_vector_type(4))) float f32x4;
typedef __attribute__((ext_vector_type(8))) short s16x8;
typedef __attribute__((ext_vector_type(4))) unsigned short u16x4;

#define DEV __device__ __forceinline__

DEV unsigned short f2bf(float f) {
  unsigned int u = __float_as_uint(f);
  return (unsigned short)((u + 0x7FFFu + ((u >> 16) & 1u)) >> 16);
}

DEV void gload_lds16(const void* g, void* l) {
  __builtin_amdgcn_global_load_lds(
      (const __attribute__((address_space(1))) unsigned int*)g,
      (__attribute__((address_space(3))) unsigned int*)l, 16, 0, 0);
}

// ---------------- LayerNorm: fp32 in -> bf16 out (rows of 1024) ----------------
__global__ __launch_bounds__(256) void ln_kernel(
    const float* __restrict__ x, const float* __restrict__ gam,
    const float* __restrict__ bet, unsigned short* __restrict__ o)
{
  const int row = blockIdx.x;
  const int tid = threadIdx.x;
  f32x4 v = *(const f32x4*)(x + (size_t)row * 1024 + tid * 4);
  float s = v[0] + v[1] + v[2] + v[3];
  float s2 = v[0]*v[0] + v[1]*v[1] + v[2]*v[2] + v[3]*v[3];
  #pragma unroll
  for (int m = 1; m < 64; m <<= 1) { s += __shfl_xor(s, m); s2 += __shfl_xor(s2, m); }
  __shared__ float ps[4], ps2[4];
  const int wid = tid >> 6, lane = tid & 63;
  if (lane == 0) { ps[wid] = s; ps2[wid] = s2; }
  __syncthreads();
  s = ps[0] + ps[1] + ps[2] + ps[3];
  s2 = ps2[0] + ps2[1] + ps2[2] + ps2[3];
  const float mu = s * (1.0f / 1024.0f);
  const float rstd = rsqrtf(s2 * (1.0f / 1024.0f) - mu * mu + 1e-5f);
  f32x4 g4 = *(const f32x4*)(gam + tid * 4);
  f32x4 b4 = *(const f32x4*)(bet + tid * 4);
  u16x4 ov;
  #pragma unroll
  for (int j = 0; j < 4; j++) ov[j] = f2bf((v[j] - mu) * rstd * g4[j] + b4[j]);
  *(u16x4*)(o + (size_t)row * 1024 + tid * 4) = ov;
}

// -------- transpose+convert: W[K][N] f32 -> WT[N][K] bf16 (64x64 LDS tiles) --------
__global__ __launch_bounds__(256) void transpose_kernel(
    const float* __restrict__ W, unsigned short* __restrict__ WT, int K, int N)
{
  __shared__ float tile[64][65];
  const int n0 = blockIdx.x * 64, k0 = blockIdx.y * 64;
  const int c = threadIdx.x & 63, r0 = threadIdx.x >> 6;
  #pragma unroll
  for (int r = r0; r < 64; r += 4)
    tile[r][c] = W[(size_t)(k0 + r) * N + n0 + c];
  __syncthreads();
  #pragma unroll
  for (int r = r0; r < 64; r += 4)
    WT[(size_t)(n0 + r) * K + k0 + c] = f2bf(tile[c][r]);
}

// ---------------- GEMM: C[M][N] = A[M][K](bf16) @ WT[N][K]^T + bias ----------------
// m97 structure: 128x128 tile, BK=32, 4 waves, 4x4 16x16x32-MFMA frags/wave,
// global_load_lds width-16 staging, 2 barriers/K-step.
// MODE 0: out bf16 = v; MODE 1: out f32 = v + resid; MODE 2: out bf16 = gelu(v)
template <int MODE>
__global__ __launch_bounds__(256) void gemm_kernel(
    const unsigned short* __restrict__ A, const unsigned short* __restrict__ WT,
    const float* __restrict__ bias, const float* resid, void* outp,
    int M, int N, int K)
{
  __shared__ unsigned short As[128 * 32];
  __shared__ unsigned short Bs[128 * 32];
  const int tid = threadIdx.x;
  const int lane = tid & 63;
  const int wid = tid >> 6;
  const int l15 = lane & 15, l4 = lane >> 4;
  const int tiles_n = N >> 7;
  const int bm = blockIdx.x / tiles_n, bn = blockIdx.x % tiles_n;
  const int wr = wid >> 1, wc = wid & 1;

  f32x4 acc[4][4] = {};

  for (int kt = 0; kt < K; kt += 32) {
    #pragma unroll
    for (int s = 0; s < 2; ++s) {
      const int c = s * 256 + tid;              // chunk id, 512 chunks of 16B
      const int rowi = c >> 2, colb = (c & 3) * 8;
      unsigned short* lbase_a = As + (size_t)(c & ~63) * 8;  // wave-uniform
      unsigned short* lbase_b = Bs + (size_t)(c & ~63) * 8;
      gload_lds16(A  + (size_t)(bm * 128 + rowi) * K + kt + colb, lbase_a);
      gload_lds16(WT + (size_t)(bn * 128 + rowi) * K + kt + colb, lbase_b);
    }
    __syncthreads();
    s16x8 af[4], bq[4];
    #pragma unroll
    for (int i = 0; i < 4; i++)
      af[i] = *(const s16x8*)&As[(wr * 64 + i * 16 + l15) * 32 + l4 * 8];
    #pragma unroll
    for (int j = 0; j < 4; j++)
      bq[j] = *(const s16x8*)&Bs[(wc * 64 + j * 16 + l15) * 32 + l4 * 8];
    #pragma unroll
    for (int i = 0; i < 4; i++)
      #pragma unroll
      for (int j = 0; j < 4; j++)
        acc[i][j] = __builtin_amdgcn_mfma_f32_16x16x32_bf16(af[i], bq[j], acc[i][j], 0, 0, 0);
    __syncthreads();
  }

  #pragma unroll
  for (int i = 0; i < 4; i++) {
    #pragma unroll
    for (int j = 0; j < 4; j++) {
      const int col = bn * 128 + wc * 64 + j * 16 + l15;
      const float bv = bias[col];
      #pragma unroll
      for (int r = 0; r < 4; r++) {
        const int row = bm * 128 + wr * 64 + i * 16 + l4 * 4 + r;
        const size_t off = (size_t)row * N + col;
        float v = acc[i][j][r] + bv;
        if (MODE == 1) {
          ((float*)outp)[off] = v + resid[off];
        } else if (MODE == 2) {
          const float t = __expf(1.5957691216f * (v + 0.044715f * v * v * v));
          ((unsigned short*)outp)[off] = f2bf(v - v / (t + 1.0f));  // tanh-gelu
        } else {
          ((unsigned short*)outp)[off] = f2bf(v);
        }
      }
    }
  }
}

// ---------------- causal flash attention ----------------
// qkv: [B,T,3072] bf16 rows = [Q(1024)|K(1024)|V(1024)], head h at h*64.
// grid: (T/64, B*H). Block = 4 waves; wave w owns 16 q-rows. KV tiles of 64.
// K staged via global_load_lds with pre-swizzled source (rule 21); V reg-staged
// transposed (Vt[d][kv]) with XOR swizzle; P per-wave LDS round-trip.
__global__ __launch_bounds__(256) void attn_kernel(
    const unsigned short* __restrict__ qkv, unsigned short* __restrict__ outb)
{
  __shared__ unsigned short Ks[64 * 64];          // [kv][d^((kv&7)<<3)]
  __shared__ unsigned short Vt[64 * 64];          // [d][kv^(((d>>2)&7)<<3)]
  __shared__ unsigned short Ps[4][16 * 64];       // per-wave P [q16][kv^((q16&7)<<3)]
  const int qb = blockIdx.x;
  const int bh = blockIdx.y;
  const int b = bh >> 4, h = bh & 15;
  const int tid = threadIdx.x, lane = tid & 63, wid = tid >> 6;
  const int l15 = lane & 15, l4 = lane >> 4;
  const size_t base = (size_t)b * 2048 * 3072 + (size_t)h * 64;
  const unsigned short* Qb = qkv + base;
  const unsigned short* Kb = qkv + base + 1024;
  const unsigned short* Vb = qkv + base + 2048;

  // Q fragments for this wave's 16 rows (held in regs across KV loop)
  s16x8 qf[2];
  {
    const unsigned short* qrow = Qb + (size_t)(qb * 64 + wid * 16 + l15) * 3072 + l4 * 8;
    qf[0] = *(const s16x8*)(qrow);
    qf[1] = *(const s16x8*)(qrow + 32);
  }
  float m_r[4], l_r[4];
  f32x4 o_acc[4];
  #pragma unroll
  for (int r = 0; r < 4; r++) { m_r[r] = -1e30f; l_r[r] = 0.f; }
  #pragma unroll
  for (int cb = 0; cb < 4; cb++) o_acc[cb] = (f32x4){0.f, 0.f, 0.f, 0.f};

  const int qg0 = qb * 64 + wid * 16 + l4 * 4;   // global q row for r=0

  for (int kvb = 0; kvb <= qb; ++kvb) {
    const int kv0 = kvb * 64;
    __syncthreads();                              // protect Ks/Vt from prev-iter readers
    // stage K: 512 chunks of 16B; source pre-swizzled so linear LDS = swizzled layout
    #pragma unroll
    for (int s = 0; s < 2; ++s) {
      const int c = s * 256 + tid;
      const int kv = c >> 3;
      const int dsrc = ((c & 7) * 8) ^ ((kv & 7) << 3);
      gload_lds16(Kb + (size_t)(kv0 + kv) * 3072 + dsrc,
                  Ks + (size_t)(c & ~63) * 8);
    }
    // stage V transposed: coalesced u16x4 global reads, swizzled LDS writes
    #pragma unroll
    for (int it = 0; it < 4; ++it) {
      const int cc = tid + 256 * it;
      const int vkv = cc >> 4;
      const int vd = (cc & 15) * 4;
      u16x4 vv = *(const u16x4*)(Vb + (size_t)(kv0 + vkv) * 3072 + vd);
      #pragma unroll
      for (int j = 0; j < 4; j++) {
        const int d = vd + j;
        Vt[d * 64 + (vkv ^ (((d >> 2) & 7) << 3))] = vv[j];
      }
    }
    __syncthreads();

    // S = (Q K^T) * 0.125, causal-masked
    f32x4 s_acc[4];
    #pragma unroll
    for (int cb = 0; cb < 4; cb++) s_acc[cb] = (f32x4){0.f, 0.f, 0.f, 0.f};
    #pragma unroll
    for (int ks = 0; ks < 2; ++ks) {
      #pragma unroll
      for (int cb = 0; cb < 4; cb++) {
        const int kvr = cb * 16 + l15;
        s16x8 bk = *(const s16x8*)&Ks[kvr * 64 + ((ks * 32 + l4 * 8) ^ ((kvr & 7) << 3))];
        s_acc[cb] = __builtin_amdgcn_mfma_f32_16x16x32_bf16(qf[ks], bk, s_acc[cb], 0, 0, 0);
      }
    }
    // online softmax (per output row r; rows live on 16-lane groups)
    #pragma unroll
    for (int r = 0; r < 4; r++) {
      float mx = -3.0e38f;
      #pragma unroll
      for (int cb = 0; cb < 4; cb++) {
        float sv = s_acc[cb][r] * 0.125f;
        const int kvg = kv0 + cb * 16 + l15;
        if (kvg > qg0 + r) sv = -3.0e38f;
        s_acc[cb][r] = sv;
        mx = fmaxf(mx, sv);
      }
      #pragma unroll
      for (int md = 1; md < 16; md <<= 1) mx = fmaxf(mx, __shfl_xor(mx, md));
      const float mnew = fmaxf(m_r[r], mx);
      const float alpha = __expf(m_r[r] - mnew);
      float rsum = 0.f;
      const int prow = l4 * 4 + r;
      #pragma unroll
      for (int cb = 0; cb < 4; cb++) {
        const float p = __expf(s_acc[cb][r] - mnew);
        rsum += p;
        const int pcol = cb * 16 + l15;
        Ps[wid][prow * 64 + (pcol ^ ((prow & 7) << 3))] = f2bf(p);
      }
      #pragma unroll
      for (int md = 1; md < 16; md <<= 1) rsum += __shfl_xor(rsum, md);
      l_r[r] = l_r[r] * alpha + rsum;
      m_r[r] = mnew;
      #pragma unroll
      for (int cb = 0; cb < 4; cb++) o_acc[cb][r] *= alpha;
    }
    asm volatile("s_waitcnt lgkmcnt(0)" ::: "memory");  // P writes visible to own wave
    // O += P @ V
    #pragma unroll
    for (int ks = 0; ks < 2; ++ks) {
      s16x8 pa = *(const s16x8*)&Ps[wid][l15 * 64 + ((ks * 32 + l4 * 8) ^ ((l15 & 7) << 3))];
      #pragma unroll
      for (int cb = 0; cb < 4; cb++) {
        const int d = cb * 16 + l15;
        s16x8 vf = *(const s16x8*)&Vt[d * 64 + ((ks * 32 + l4 * 8) ^ (((d >> 2) & 7) << 3))];
        o_acc[cb] = __builtin_amdgcn_mfma_f32_16x16x32_bf16(pa, vf, o_acc[cb], 0, 0, 0);
      }
    }
  }
  // normalize + write out[b, q, h*64+d] (bf16)
  unsigned short* orow = outb + ((size_t)b * 2048 + qb * 64 + wid * 16) * 1024 + h * 64;
  float inv[4];
  #pragma unroll
  for (int r = 0; r < 4; r++) inv[r] = 1.0f / l_r[r];
  #pragma unroll
  for (int cb = 0; cb < 4; cb++)
    #pragma unroll
    for (int r = 0; r < 4; r++)
      orow[(l4 * 4 + r) * 1024 + cb * 16 + l15] = f2bf(o_acc[cb][r] * inv[r]);
}

// ---------------- host ----------------
extern "C" void kernel_launch(void* const* d_in, const int* in_sizes, int n_in,
                              void* d_out, int out_size, void* d_ws, size_t ws_size,
                              hipStream_t stream) {
  const float* x      = (const float*)d_in[0];
  const float* ln1_g  = (const float*)d_in[1];
  const float* ln1_b  = (const float*)d_in[2];
  const float* qkv_w  = (const float*)d_in[3];
  const float* qkv_b  = (const float*)d_in[4];
  const float* proj_w = (const float*)d_in[5];
  const float* proj_b = (const float*)d_in[6];
  const float* ln2_g  = (const float*)d_in[7];
  const float* ln2_b  = (const float*)d_in[8];
  const float* ff1_w  = (const float*)d_in[9];
  const float* ff1_b  = (const float*)d_in[10];
  const float* ff2_w  = (const float*)d_in[11];
  const float* ff2_b  = (const float*)d_in[12];
  float* out = (float*)d_out;

  char* ws = (char*)d_ws;
  size_t off = 0;
  unsigned short* wbuf   = (unsigned short*)(ws + off); off += (size_t)4096 * 1024 * 2;  // 8 MiB
  unsigned short* hbuf   = (unsigned short*)(ws + off); off += (size_t)8192 * 1024 * 2;  // 16 MiB
  unsigned short* qkvbuf = (unsigned short*)(ws + off); off += (size_t)8192 * 3072 * 2;  // 48 MiB
  unsigned short* gbuf   = (unsigned short*)(ws + off);                                   // 64 MiB

  // ---- attention sublayer ----
  ln_kernel<<<8192, 256, 0, stream>>>(x, ln1_g, ln1_b, hbuf);
  transpose_kernel<<<dim3(3072 / 64, 1024 / 64), 256, 0, stream>>>(qkv_w, wbuf, 1024, 3072);
  gemm_kernel<0><<<dim3(64 * 24), 256, 0, stream>>>(hbuf, wbuf, qkv_b, nullptr, qkvbuf,
                                                    8192, 3072, 1024);
  attn_kernel<<<dim3(32, 64), 256, 0, stream>>>(qkvbuf, hbuf);
  transpose_kernel<<<dim3(1024 / 64, 1024 / 64), 256, 0, stream>>>(proj_w, wbuf, 1024, 1024);
  gemm_kernel<1><<<dim3(64 * 8), 256, 0, stream>>>(hbuf, wbuf, proj_b, x, out,
                                                   8192, 1024, 1024);   // x1 -> d_out (f32)
  // ---- MLP sublayer ----
  ln_kernel<<<8192, 256, 0, stream>>>(out, ln2_g, ln2_b, hbuf);
  transpose_kernel<<<dim3(4096 / 64, 1024 / 64), 256, 0, stream>>>(ff1_w, wbuf, 1024, 4096);
  gemm_kernel<2><<<dim3(64 * 32), 256, 0, stream>>>(hbuf, wbuf, ff1_b, nullptr, gbuf,
                                                    8192, 4096, 1024);  // gelu
  transpose_kernel<<<dim3(1024 / 64, 4096 / 64), 256, 0, stream>>>(ff2_w, wbuf, 4096, 1024);
  gemm_kernel<1><<<dim3(64 * 8), 256, 0, stream>>>(gbuf, wbuf, ff2_b, out, out,
                                                   8192, 1024, 4096);   // + x1 in-place
}

// Round 2
// 534.197 us; speedup vs baseline: 1.2847x; 1.2847x over previous
//
#include <hip/hip_runtime.h>

typedef __attribute__((ext_vector_type(4))) float f32x4;
typedef __attribute__((ext_vector_type(8))) short s16x8;
typedef __attribute__((ext_vector_type(4))) unsigned short u16x4;

#define DEV __device__ __forceinline__

DEV unsigned short f2bf(float f) {
  unsigned int u = __float_as_uint(f);
  return (unsigned short)((u + 0x7FFFu + ((u >> 16) & 1u)) >> 16);
}

DEV void gload_lds16(const void* g, void* l) {
  __builtin_amdgcn_global_load_lds(
      (const __attribute__((address_space(1))) unsigned int*)g,
      (__attribute__((address_space(3))) unsigned int*)l, 16, 0, 0);
}

// ---------------- LayerNorm: fp32 in -> bf16 out (rows of 1024) ----------------
__global__ __launch_bounds__(256) void ln_kernel(
    const float* __restrict__ x, const float* __restrict__ gam,
    const float* __restrict__ bet, unsigned short* __restrict__ o)
{
  const int row = blockIdx.x;
  const int tid = threadIdx.x;
  f32x4 v = *(const f32x4*)(x + (size_t)row * 1024 + tid * 4);
  float s = v[0] + v[1] + v[2] + v[3];
  float s2 = v[0]*v[0] + v[1]*v[1] + v[2]*v[2] + v[3]*v[3];
  #pragma unroll
  for (int m = 1; m < 64; m <<= 1) { s += __shfl_xor(s, m); s2 += __shfl_xor(s2, m); }
  __shared__ float ps[4], ps2[4];
  const int wid = tid >> 6, lane = tid & 63;
  if (lane == 0) { ps[wid] = s; ps2[wid] = s2; }
  __syncthreads();
  s = ps[0] + ps[1] + ps[2] + ps[3];
  s2 = ps2[0] + ps2[1] + ps2[2] + ps2[3];
  const float mu = s * (1.0f / 1024.0f);
  const float rstd = rsqrtf(s2 * (1.0f / 1024.0f) - mu * mu + 1e-5f);
  f32x4 g4 = *(const f32x4*)(gam + tid * 4);
  f32x4 b4 = *(const f32x4*)(bet + tid * 4);
  u16x4 ov;
  #pragma unroll
  for (int j = 0; j < 4; j++) ov[j] = f2bf((v[j] - mu) * rstd * g4[j] + b4[j]);
  *(u16x4*)(o + (size_t)row * 1024 + tid * 4) = ov;
}

// -------- transpose+convert: W[K][N] f32 -> WT[N][K] bf16 (64x64 LDS tiles) --------
__global__ __launch_bounds__(256) void transpose_kernel(
    const float* __restrict__ W, unsigned short* __restrict__ WT, int K, int N)
{
  __shared__ float tile[64][65];
  const int n0 = blockIdx.x * 64, k0 = blockIdx.y * 64;
  const int c = threadIdx.x & 63, r0 = threadIdx.x >> 6;
  #pragma unroll
  for (int r = r0; r < 64; r += 4)
    tile[r][c] = W[(size_t)(k0 + r) * N + n0 + c];
  __syncthreads();
  #pragma unroll
  for (int r = r0; r < 64; r += 4)
    WT[(size_t)(n0 + r) * K + k0 + c] = f2bf(tile[c][r]);
}

// ---------------- GEMM: C[M][N] = A[M][K](bf16) @ WT[N][K]^T + bias ----------------
// m97 structure + T1 bijective XCD swizzle (all grids %8==0).
// MODE 0: out bf16 = v; MODE 1: out f32 = v + resid; MODE 2: out bf16 = gelu(v)
template <int MODE>
__global__ __launch_bounds__(256) void gemm_kernel(
    const unsigned short* __restrict__ A, const unsigned short* __restrict__ WT,
    const float* __restrict__ bias, const float* resid, void* outp,
    int M, int N, int K)
{
  __shared__ unsigned short As[128 * 32];
  __shared__ unsigned short Bs[128 * 32];
  const int tid = threadIdx.x;
  const int lane = tid & 63;
  const int wid = tid >> 6;
  const int l15 = lane & 15, l4 = lane >> 4;
  const int tiles_n = N >> 7;
  // XCD-aware swizzle: grid %8==0 for all our shapes
  const int cpx = gridDim.x >> 3;
  const int id = (blockIdx.x & 7) * cpx + (blockIdx.x >> 3);
  const int bm = id / tiles_n, bn = id % tiles_n;
  const int wr = wid >> 1, wc = wid & 1;

  f32x4 acc[4][4] = {};

  for (int kt = 0; kt < K; kt += 32) {
    #pragma unroll
    for (int s = 0; s < 2; ++s) {
      const int c = s * 256 + tid;              // chunk id, 512 chunks of 16B
      const int rowi = c >> 2, colb = (c & 3) * 8;
      unsigned short* lbase_a = As + (size_t)(c & ~63) * 8;  // wave-uniform
      unsigned short* lbase_b = Bs + (size_t)(c & ~63) * 8;
      gload_lds16(A  + (size_t)(bm * 128 + rowi) * K + kt + colb, lbase_a);
      gload_lds16(WT + (size_t)(bn * 128 + rowi) * K + kt + colb, lbase_b);
    }
    __syncthreads();
    s16x8 af[4], bq[4];
    #pragma unroll
    for (int i = 0; i < 4; i++)
      af[i] = *(const s16x8*)&As[(wr * 64 + i * 16 + l15) * 32 + l4 * 8];
    #pragma unroll
    for (int j = 0; j < 4; j++)
      bq[j] = *(const s16x8*)&Bs[(wc * 64 + j * 16 + l15) * 32 + l4 * 8];
    #pragma unroll
    for (int i = 0; i < 4; i++)
      #pragma unroll
      for (int j = 0; j < 4; j++)
        acc[i][j] = __builtin_amdgcn_mfma_f32_16x16x32_bf16(af[i], bq[j], acc[i][j], 0, 0, 0);
    __syncthreads();
  }

  #pragma unroll
  for (int i = 0; i < 4; i++) {
    #pragma unroll
    for (int j = 0; j < 4; j++) {
      const int col = bn * 128 + wc * 64 + j * 16 + l15;
      const float bv = bias[col];
      #pragma unroll
      for (int r = 0; r < 4; r++) {
        const int row = bm * 128 + wr * 64 + i * 16 + l4 * 4 + r;
        const size_t off = (size_t)row * N + col;
        float v = acc[i][j][r] + bv;
        if (MODE == 1) {
          ((float*)outp)[off] = v + resid[off];
        } else if (MODE == 2) {
          const float t = __expf(1.5957691216f * (v + 0.044715f * v * v * v));
          ((unsigned short*)outp)[off] = f2bf(v - v / (t + 1.0f));  // tanh-gelu
        } else {
          ((unsigned short*)outp)[off] = f2bf(v);
        }
      }
    }
  }
}

// ---------------- causal flash attention (paired tiles + swapped QK^T) ----------------
// qkv: [B,T,3072] bf16 rows = [Q(1024)|K(1024)|V(1024)], head h at h*64.
// grid: (16, B*H). Block pid handles q-tiles qA=pid and qB=31-pid -> uniform
// 33 tile-computes/block; 1024 blocks = exactly 4/CU all-resident.
// Swapped QK^T: S^T = mfma(K,Q); lane owns q = lane&15, kv in regs ->
// softmax reduce = in-lane + 2 shfl_xor; alpha broadcast via 4 shfl.

struct AttnState {
  f32x4 o[4];
  float m, l;
};

DEV void attn_tile(const s16x8* qf, const unsigned short* Ks,
                   const unsigned short* Vt, unsigned short* Pw,
                   AttnState& st, int kv0, int qg, int l15, int l4, bool need_mask)
{
  // S^T = (K Q^T): D col = q = l15, D row = kv-local = l4*4 + r (+ cb*16)
  f32x4 sa[4];
  #pragma unroll
  for (int cb = 0; cb < 4; cb++) sa[cb] = (f32x4){0.f, 0.f, 0.f, 0.f};
  __builtin_amdgcn_s_setprio(1);
  #pragma unroll
  for (int ks = 0; ks < 2; ++ks) {
    #pragma unroll
    for (int cb = 0; cb < 4; cb++) {
      const int kvr = cb * 16 + l15;
      s16x8 bk = *(const s16x8*)&Ks[kvr * 64 + ((ks * 32 + l4 * 8) ^ ((kvr & 7) << 3))];
      sa[cb] = __builtin_amdgcn_mfma_f32_16x16x32_bf16(bk, qf[ks], sa[cb], 0, 0, 0);
    }
  }
  __builtin_amdgcn_s_setprio(0);
  // masked scale + in-lane max (all 16 values belong to q = l15)
  float mx = -3.0e38f;
  const int thr = qg - kv0 - l4 * 4;          // mask if cb*16 + r > thr
  #pragma unroll
  for (int cb = 0; cb < 4; cb++)
    #pragma unroll
    for (int r = 0; r < 4; r++) {
      float sv = sa[cb][r] * 0.125f;
      if (need_mask && (cb * 16 + r > thr)) sv = -3.0e38f;
      sa[cb][r] = sv;
      mx = fmaxf(mx, sv);
    }
  mx = fmaxf(mx, __shfl_xor(mx, 16));
  mx = fmaxf(mx, __shfl_xor(mx, 32));
  const float mnew = fmaxf(st.m, mx);
  const float alpha = __expf(st.m - mnew);
  st.m = mnew;
  float rsum = 0.f;
  #pragma unroll
  for (int cb = 0; cb < 4; cb++) {
    u16x4 pw;
    #pragma unroll
    for (int r = 0; r < 4; r++) {
      const float p = __expf(sa[cb][r] - mnew);
      rsum += p;
      pw[r] = f2bf(p);
    }
    *(u16x4*)&Pw[l15 * 64 + ((cb * 16 + l4 * 4) ^ ((l15 & 7) << 3))] = pw;
  }
  rsum += __shfl_xor(rsum, 16);
  rsum += __shfl_xor(rsum, 32);
  st.l = st.l * alpha + rsum;
  // rescale O rows (row q-local = l4*4+r needs alpha from lane l4*4+r)
  #pragma unroll
  for (int r = 0; r < 4; r++) {
    const float ar = __shfl(alpha, l4 * 4 + r);
    #pragma unroll
    for (int cb = 0; cb < 4; cb++) st.o[cb][r] *= ar;
  }
  asm volatile("s_waitcnt lgkmcnt(0)" ::: "memory");  // P writes visible to own wave
  // O += P @ V
  __builtin_amdgcn_s_setprio(1);
  #pragma unroll
  for (int ks = 0; ks < 2; ++ks) {
    s16x8 pa = *(const s16x8*)&Pw[l15 * 64 + ((ks * 32 + l4 * 8) ^ ((l15 & 7) << 3))];
    #pragma unroll
    for (int cb = 0; cb < 4; cb++) {
      const int d = cb * 16 + l15;
      s16x8 vf = *(const s16x8*)&Vt[d * 64 + ((ks * 32 + l4 * 8) ^ (((d >> 2) & 7) << 3))];
      st.o[cb] = __builtin_amdgcn_mfma_f32_16x16x32_bf16(pa, vf, st.o[cb], 0, 0, 0);
    }
  }
  __builtin_amdgcn_s_setprio(0);
}

DEV void attn_write(unsigned short* orow, const AttnState& st, int l15, int l4) {
  const float invl = 1.0f / st.l;             // valid for q = l15
  #pragma unroll
  for (int r = 0; r < 4; r++) {
    const float ir = __shfl(invl, l4 * 4 + r);
    #pragma unroll
    for (int cb = 0; cb < 4; cb++)
      orow[(l4 * 4 + r) * 1024 + cb * 16 + l15] = f2bf(st.o[cb][r] * ir);
  }
}

__global__ __launch_bounds__(256) void attn_kernel(
    const unsigned short* __restrict__ qkv, unsigned short* __restrict__ outb)
{
  __shared__ unsigned short Ks[64 * 64];          // [kv][d^((kv&7)<<3)]
  __shared__ unsigned short Vt[64 * 64];          // [d][kv^(((d>>2)&7)<<3)]
  __shared__ unsigned short Ps[2][4][16 * 64];    // per-tile, per-wave P
  const int pid = blockIdx.x;                     // 0..15
  const int qA = pid, qB = 31 - pid;
  const int bh = blockIdx.y;
  const int b = bh >> 4, h = bh & 15;
  const int tid = threadIdx.x, lane = tid & 63, wid = tid >> 6;
  const int l15 = lane & 15, l4 = lane >> 4;
  const size_t base = (size_t)b * 2048 * 3072 + (size_t)h * 64;
  const unsigned short* Qb = qkv + base;
  const unsigned short* Kb = qkv + base + 1024;
  const unsigned short* Vb = qkv + base + 2048;

  s16x8 qfA[2], qfB[2];
  {
    const unsigned short* qr = Qb + (size_t)(qA * 64 + wid * 16 + l15) * 3072 + l4 * 8;
    qfA[0] = *(const s16x8*)qr;
    qfA[1] = *(const s16x8*)(qr + 32);
    qr = Qb + (size_t)(qB * 64 + wid * 16 + l15) * 3072 + l4 * 8;
    qfB[0] = *(const s16x8*)qr;
    qfB[1] = *(const s16x8*)(qr + 32);
  }
  AttnState sA, sB;
  #pragma unroll
  for (int cb = 0; cb < 4; cb++) {
    sA.o[cb] = (f32x4){0.f, 0.f, 0.f, 0.f};
    sB.o[cb] = (f32x4){0.f, 0.f, 0.f, 0.f};
  }
  sA.m = -1e30f; sA.l = 0.f; sB.m = -1e30f; sB.l = 0.f;
  const int qgA = qA * 64 + wid * 16 + l15;
  const int qgB = qB * 64 + wid * 16 + l15;

  for (int kvb = 0; kvb <= qB; ++kvb) {
    const int kv0 = kvb * 64;
    __syncthreads();                              // protect Ks/Vt/Ps from prev readers
    // stage K: pre-swizzled source, linear LDS dest (rule 21)
    #pragma unroll
    for (int s = 0; s < 2; ++s) {
      const int c = s * 256 + tid;
      const int kv = c >> 3;
      const int dsrc = ((c & 7) * 8) ^ ((kv & 7) << 3);
      gload_lds16(Kb + (size_t)(kv0 + kv) * 3072 + dsrc,
                  Ks + (size_t)(c & ~63) * 8);
    }
    // stage V transposed: coalesced u16x4 global reads, swizzled LDS writes
    #pragma unroll
    for (int it = 0; it < 4; ++it) {
      const int cc = tid + 256 * it;
      const int vkv = cc >> 4;
      const int vd = (cc & 15) * 4;
      u16x4 vv = *(const u16x4*)(Vb + (size_t)(kv0 + vkv) * 3072 + vd);
      #pragma unroll
      for (int j = 0; j < 4; j++) {
        const int d = vd + j;
        Vt[d * 64 + (vkv ^ (((d >> 2) & 7) << 3))] = vv[j];
      }
    }
    __syncthreads();

    if (kvb <= qA)
      attn_tile(qfA, Ks, Vt, Ps[0][wid], sA, kv0, qgA, l15, l4,
                kv0 + 63 > qA * 64 + wid * 16);
    attn_tile(qfB, Ks, Vt, Ps[1][wid], sB, kv0, qgB, l15, l4,
              kv0 + 63 > qB * 64 + wid * 16);
  }
  attn_write(outb + ((size_t)b * 2048 + qA * 64 + wid * 16) * 1024 + h * 64, sA, l15, l4);
  attn_write(outb + ((size_t)b * 2048 + qB * 64 + wid * 16) * 1024 + h * 64, sB, l15, l4);
}

// ---------------- host ----------------
extern "C" void kernel_launch(void* const* d_in, const int* in_sizes, int n_in,
                              void* d_out, int out_size, void* d_ws, size_t ws_size,
                              hipStream_t stream) {
  const float* x      = (const float*)d_in[0];
  const float* ln1_g  = (const float*)d_in[1];
  const float* ln1_b  = (const float*)d_in[2];
  const float* qkv_w  = (const float*)d_in[3];
  const float* qkv_b  = (const float*)d_in[4];
  const float* proj_w = (const float*)d_in[5];
  const float* proj_b = (const float*)d_in[6];
  const float* ln2_g  = (const float*)d_in[7];
  const float* ln2_b  = (const float*)d_in[8];
  const float* ff1_w  = (const float*)d_in[9];
  const float* ff1_b  = (const float*)d_in[10];
  const float* ff2_w  = (const float*)d_in[11];
  const float* ff2_b  = (const float*)d_in[12];
  float* out = (float*)d_out;

  char* ws = (char*)d_ws;
  size_t off = 0;
  unsigned short* wbuf   = (unsigned short*)(ws + off); off += (size_t)4096 * 1024 * 2;  // 8 MiB
  unsigned short* hbuf   = (unsigned short*)(ws + off); off += (size_t)8192 * 1024 * 2;  // 16 MiB
  unsigned short* qkvbuf = (unsigned short*)(ws + off); off += (size_t)8192 * 3072 * 2;  // 48 MiB
  unsigned short* gbuf   = (unsigned short*)(ws + off);                                   // 64 MiB

  // ---- attention sublayer ----
  ln_kernel<<<8192, 256, 0, stream>>>(x, ln1_g, ln1_b, hbuf);
  transpose_kernel<<<dim3(3072 / 64, 1024 / 64), 256, 0, stream>>>(qkv_w, wbuf, 1024, 3072);
  gemm_kernel<0><<<dim3(64 * 24), 256, 0, stream>>>(hbuf, wbuf, qkv_b, nullptr, qkvbuf,
                                                    8192, 3072, 1024);
  attn_kernel<<<dim3(16, 64), 256, 0, stream>>>(qkvbuf, hbuf);
  transpose_kernel<<<dim3(1024 / 64, 1024 / 64), 256, 0, stream>>>(proj_w, wbuf, 1024, 1024);
  gemm_kernel<1><<<dim3(64 * 8), 256, 0, stream>>>(hbuf, wbuf, proj_b, x, out,
                                                   8192, 1024, 1024);   // x1 -> d_out (f32)
  // ---- MLP sublayer ----
  ln_kernel<<<8192, 256, 0, stream>>>(out, ln2_g, ln2_b, hbuf);
  transpose_kernel<<<dim3(4096 / 64, 1024 / 64), 256, 0, stream>>>(ff1_w, wbuf, 1024, 4096);
  gemm_kernel<2><<<dim3(64 * 32), 256, 0, stream>>>(hbuf, wbuf, ff1_b, nullptr, gbuf,
                                                    8192, 4096, 1024);  // gelu
  transpose_kernel<<<dim3(1024 / 64, 4096 / 64), 256, 0, stream>>>(ff2_w, wbuf, 4096, 1024);
  gemm_kernel<1><<<dim3(64 * 8), 256, 0, stream>>>(gbuf, wbuf, ff2_b, out, out,
                                                   8192, 1024, 4096);   // + x1 in-place
}

// Round 3
// 515.419 us; speedup vs baseline: 1.3315x; 1.0364x over previous
//
#include <hip/hip_runtime.h>

typedef __attribute__((ext_vector_type(4))) float f32x4;
typedef __attribute__((ext_vector_type(8))) short s16x8;
typedef __attribute__((ext_vector_type(4))) unsigned short u16x4;

#define DEV __device__ __forceinline__

DEV unsigned short f2bf(float f) {
  unsigned int u = __float_as_uint(f);
  return (unsigned short)((u + 0x7FFFu + ((u >> 16) & 1u)) >> 16);
}

DEV void gload_lds16(const void* g, void* l) {
  __builtin_amdgcn_global_load_lds(
      (const __attribute__((address_space(1))) unsigned int*)g,
      (__attribute__((address_space(3))) unsigned int*)l, 16, 0, 0);
}

// ---------------- LayerNorm: fp32 in -> bf16 out (rows of 1024) ----------------
__global__ __launch_bounds__(256) void ln_kernel(
    const float* __restrict__ x, const float* __restrict__ gam,
    const float* __restrict__ bet, unsigned short* __restrict__ o)
{
  const int row = blockIdx.x;
  const int tid = threadIdx.x;
  f32x4 v = *(const f32x4*)(x + (size_t)row * 1024 + tid * 4);
  float s = v[0] + v[1] + v[2] + v[3];
  float s2 = v[0]*v[0] + v[1]*v[1] + v[2]*v[2] + v[3]*v[3];
  #pragma unroll
  for (int m = 1; m < 64; m <<= 1) { s += __shfl_xor(s, m); s2 += __shfl_xor(s2, m); }
  __shared__ float ps[4], ps2[4];
  const int wid = tid >> 6, lane = tid & 63;
  if (lane == 0) { ps[wid] = s; ps2[wid] = s2; }
  __syncthreads();
  s = ps[0] + ps[1] + ps[2] + ps[3];
  s2 = ps2[0] + ps2[1] + ps2[2] + ps2[3];
  const float mu = s * (1.0f / 1024.0f);
  const float rstd = rsqrtf(s2 * (1.0f / 1024.0f) - mu * mu + 1e-5f);
  f32x4 g4 = *(const f32x4*)(gam + tid * 4);
  f32x4 b4 = *(const f32x4*)(bet + tid * 4);
  u16x4 ov;
  #pragma unroll
  for (int j = 0; j < 4; j++) ov[j] = f2bf((v[j] - mu) * rstd * g4[j] + b4[j]);
  *(u16x4*)(o + (size_t)row * 1024 + tid * 4) = ov;
}

// -------- transpose+convert: W[K][N] f32 -> WT[N][K] bf16 (64x64 LDS tiles) --------
__global__ __launch_bounds__(256) void transpose_kernel(
    const float* __restrict__ W, unsigned short* __restrict__ WT, int K, int N)
{
  __shared__ float tile[64][65];
  const int n0 = blockIdx.x * 64, k0 = blockIdx.y * 64;
  const int c = threadIdx.x & 63, r0 = threadIdx.x >> 6;
  #pragma unroll
  for (int r = r0; r < 64; r += 4)
    tile[r][c] = W[(size_t)(k0 + r) * N + n0 + c];
  __syncthreads();
  #pragma unroll
  for (int r = r0; r < 64; r += 4)
    WT[(size_t)(n0 + r) * K + k0 + c] = f2bf(tile[c][r]);
}

// ---------------- m97-style 128x128 GEMM (kept for N=1024 shapes) ----------------
// MODE 0: out bf16 = v; MODE 1: out f32 = v + resid; MODE 2: out bf16 = gelu(v)
template <int MODE>
__global__ __launch_bounds__(256) void gemm_kernel(
    const unsigned short* __restrict__ A, const unsigned short* __restrict__ WT,
    const float* __restrict__ bias, const float* resid, void* outp,
    int M, int N, int K)
{
  __shared__ unsigned short As[128 * 32];
  __shared__ unsigned short Bs[128 * 32];
  const int tid = threadIdx.x;
  const int lane = tid & 63;
  const int wid = tid >> 6;
  const int l15 = lane & 15, l4 = lane >> 4;
  const int tiles_n = N >> 7;
  const int cpx = gridDim.x >> 3;
  const int id = (blockIdx.x & 7) * cpx + (blockIdx.x >> 3);
  const int bm = id / tiles_n, bn = id % tiles_n;
  const int wr = wid >> 1, wc = wid & 1;

  f32x4 acc[4][4] = {};

  for (int kt = 0; kt < K; kt += 32) {
    #pragma unroll
    for (int s = 0; s < 2; ++s) {
      const int c = s * 256 + tid;
      const int rowi = c >> 2, colb = (c & 3) * 8;
      unsigned short* lbase_a = As + (size_t)(c & ~63) * 8;
      unsigned short* lbase_b = Bs + (size_t)(c & ~63) * 8;
      gload_lds16(A  + (size_t)(bm * 128 + rowi) * K + kt + colb, lbase_a);
      gload_lds16(WT + (size_t)(bn * 128 + rowi) * K + kt + colb, lbase_b);
    }
    __syncthreads();
    s16x8 af[4], bq[4];
    #pragma unroll
    for (int i = 0; i < 4; i++)
      af[i] = *(const s16x8*)&As[(wr * 64 + i * 16 + l15) * 32 + l4 * 8];
    #pragma unroll
    for (int j = 0; j < 4; j++)
      bq[j] = *(const s16x8*)&Bs[(wc * 64 + j * 16 + l15) * 32 + l4 * 8];
    #pragma unroll
    for (int i = 0; i < 4; i++)
      #pragma unroll
      for (int j = 0; j < 4; j++)
        acc[i][j] = __builtin_amdgcn_mfma_f32_16x16x32_bf16(af[i], bq[j], acc[i][j], 0, 0, 0);
    __syncthreads();
  }

  #pragma unroll
  for (int i = 0; i < 4; i++) {
    #pragma unroll
    for (int j = 0; j < 4; j++) {
      const int col = bn * 128 + wc * 64 + j * 16 + l15;
      const float bv = bias[col];
      #pragma unroll
      for (int r = 0; r < 4; r++) {
        const int row = bm * 128 + wr * 64 + i * 16 + l4 * 4 + r;
        const size_t off = (size_t)row * N + col;
        float v = acc[i][j][r] + bv;
        if (MODE == 1) {
          ((float*)outp)[off] = v + resid[off];
        } else if (MODE == 2) {
          const float t = __expf(1.5957691216f * (v + 0.044715f * v * v * v));
          ((unsigned short*)outp)[off] = f2bf(v - v / (t + 1.0f));
        } else {
          ((unsigned short*)outp)[off] = f2bf(v);
        }
      }
    }
  }
}

// ---------------- 8-phase 256x256 GEMM, BK=32, 4-slot LDS ring ----------------
// 8 waves (2M x 4N), per-wave C = 128x64 (8x4 16x16 frags). 2 phases per K-tile,
// 16 MFMA each. Prefetch 3 tiles ahead via global_load_lds; per-tile counted
// vmcnt(8) (tiles t+2,t+3 in flight) before final barrier -> tile t+1 landed
// for ALL waves. BK=32 row stride (64B) keeps ds_read_b128 bank-balanced
// without swizzle. Ring slot (t+3)&3: last read in tile t-1, drained by that
// tile's lgkmcnt(0) before its final barrier -> no write-before-read race.
template <int MODE>
__global__ __launch_bounds__(512) void gemm8_kernel(
    const unsigned short* __restrict__ A, const unsigned short* __restrict__ WT,
    const float* __restrict__ bias, const float* resid, void* outp,
    int M, int N, int K)
{
  __shared__ unsigned short lds[4 * 16384];   // 4 slots x (A 8K + B 8K shorts) = 128 KiB
  const int tid = threadIdx.x;
  const int lane = tid & 63, wid = tid >> 6;
  const int l15 = lane & 15, l4 = lane >> 4;
  const int wm = wid >> 2, wn = wid & 3;
  const int tiles_n = N >> 8;
  const int cpx = gridDim.x >> 3;
  const int id = (blockIdx.x & 7) * cpx + (blockIdx.x >> 3);
  const int bm = id / tiles_n, bn = id % tiles_n;
  const int NT = K >> 5;

  // staging: thread t covers LDS shorts [t*8 + j*4096, +8) of a 16KB unit
  //   -> row (t>>2)+j*128, col chunk (t&3)*8 of the 256x32 tile (linear layout)
  const int srow = tid >> 2;
  const int scol = (tid & 3) * 8;
  const unsigned short* Abase = A  + (size_t)(bm * 256 + srow) * K + scol;
  const unsigned short* Bbase = WT + (size_t)(bn * 256 + srow) * K + scol;
  const size_t jstride = (size_t)128 * K;
  const int dstoff = wid * 512;                // + j*4096, wave-uniform

  f32x4 acc[8][4] = {};

  const int aoff = (wm * 128 + l15) * 32 + l4 * 8;   // + mf*512
  const int boff = (wn * 64 + l15) * 32 + l4 * 8;    // + nf*512

#define STAGE_A(t_) { unsigned short* s_ = lds + ((t_) & 3) * 16384; \
    gload_lds16(Abase + (size_t)(t_) * 32,           s_ + dstoff); \
    gload_lds16(Abase + jstride + (size_t)(t_) * 32, s_ + 4096 + dstoff); }
#define STAGE_B(t_) { unsigned short* s_ = lds + ((t_) & 3) * 16384 + 8192; \
    gload_lds16(Bbase + (size_t)(t_) * 32,           s_ + dstoff); \
    gload_lds16(Bbase + jstride + (size_t)(t_) * 32, s_ + 4096 + dstoff); }

  // prologue: tiles 0,1,2 in flight; wait own tile-0 loads (oldest 4), barrier
  STAGE_A(0); STAGE_B(0);
  STAGE_A(1); STAGE_B(1);
  STAGE_A(2); STAGE_B(2);
  asm volatile("s_waitcnt vmcnt(8)" ::: "memory");
  __builtin_amdgcn_s_barrier();

  for (int t = 0; t < NT; ++t) {
    const unsigned short* sa = lds + (t & 3) * 16384;
    const unsigned short* sb = sa + 8192;
    s16x8 af[4], bf[4];
    // ---- phase 0: C rows wm*128+[0,64), all 4 nf ----
    #pragma unroll
    for (int mf = 0; mf < 4; mf++) af[mf] = *(const s16x8*)&sa[aoff + mf * 512];
    #pragma unroll
    for (int nf = 0; nf < 4; nf++) bf[nf] = *(const s16x8*)&sb[boff + nf * 512];
    if (t + 3 < NT) STAGE_A(t + 3);
    __builtin_amdgcn_s_barrier();
    asm volatile("s_waitcnt lgkmcnt(0)" ::: "memory");
    __builtin_amdgcn_sched_barrier(0);
    __builtin_amdgcn_s_setprio(1);
    #pragma unroll
    for (int mf = 0; mf < 4; mf++)
      #pragma unroll
      for (int nf = 0; nf < 4; nf++)
        acc[mf][nf] = __builtin_amdgcn_mfma_f32_16x16x32_bf16(af[mf], bf[nf], acc[mf][nf], 0, 0, 0);
    __builtin_amdgcn_s_setprio(0);
    __builtin_amdgcn_s_barrier();
    // ---- phase 1: C rows wm*128+[64,128), reuse bf ----
    #pragma unroll
    for (int mf = 0; mf < 4; mf++) af[mf] = *(const s16x8*)&sa[aoff + (4 + mf) * 512];
    if (t + 3 < NT) STAGE_B(t + 3);
    __builtin_amdgcn_s_barrier();
    asm volatile("s_waitcnt lgkmcnt(0)" ::: "memory");
    __builtin_amdgcn_sched_barrier(0);
    __builtin_amdgcn_s_setprio(1);
    #pragma unroll
    for (int mf = 0; mf < 4; mf++)
      #pragma unroll
      for (int nf = 0; nf < 4; nf++)
        acc[4 + mf][nf] = __builtin_amdgcn_mfma_f32_16x16x32_bf16(af[mf], bf[nf], acc[4 + mf][nf], 0, 0, 0);
    __builtin_amdgcn_s_setprio(0);
    // counted wait so next tile's (t+1) loads are landed after the barrier;
    // tiles t+2 (4 loads) and t+3 (4 loads) may stay in flight. Tail drains.
    if (t + 3 < NT)      { asm volatile("s_waitcnt vmcnt(8)" ::: "memory"); }
    else if (t + 2 < NT) { asm volatile("s_waitcnt vmcnt(4)" ::: "memory"); }
    else if (t + 1 < NT) { asm volatile("s_waitcnt vmcnt(0)" ::: "memory"); }
    __builtin_amdgcn_s_barrier();
  }
#undef STAGE_A
#undef STAGE_B

  #pragma unroll
  for (int nf = 0; nf < 4; nf++) {
    const int col = bn * 256 + wn * 64 + nf * 16 + l15;
    const float bv = bias[col];
    #pragma unroll
    for (int mf = 0; mf < 8; mf++) {
      #pragma unroll
      for (int r = 0; r < 4; r++) {
        const int row = bm * 256 + wm * 128 + mf * 16 + l4 * 4 + r;
        const size_t off = (size_t)row * N + col;
        float v = acc[mf][nf][r] + bv;
        if (MODE == 1) {
          ((float*)outp)[off] = v + resid[off];
        } else if (MODE == 2) {
          const float tt = __expf(1.5957691216f * (v + 0.044715f * v * v * v));
          ((unsigned short*)outp)[off] = f2bf(v - v / (tt + 1.0f));
        } else {
          ((unsigned short*)outp)[off] = f2bf(v);
        }
      }
    }
  }
}

// ---------------- causal flash attention (paired tiles + swapped QK^T) ----------------
struct AttnState {
  f32x4 o[4];
  float m, l;
};

DEV void attn_tile(const s16x8* qf, const unsigned short* Ks,
                   const unsigned short* Vt, unsigned short* Pw,
                   AttnState& st, int kv0, int qg, int l15, int l4, bool need_mask)
{
  f32x4 sa[4];
  #pragma unroll
  for (int cb = 0; cb < 4; cb++) sa[cb] = (f32x4){0.f, 0.f, 0.f, 0.f};
  __builtin_amdgcn_s_setprio(1);
  #pragma unroll
  for (int ks = 0; ks < 2; ++ks) {
    #pragma unroll
    for (int cb = 0; cb < 4; cb++) {
      const int kvr = cb * 16 + l15;
      s16x8 bk = *(const s16x8*)&Ks[kvr * 64 + ((ks * 32 + l4 * 8) ^ ((kvr & 7) << 3))];
      sa[cb] = __builtin_amdgcn_mfma_f32_16x16x32_bf16(bk, qf[ks], sa[cb], 0, 0, 0);
    }
  }
  __builtin_amdgcn_s_setprio(0);
  float mx = -3.0e38f;
  const int thr = qg - kv0 - l4 * 4;
  #pragma unroll
  for (int cb = 0; cb < 4; cb++)
    #pragma unroll
    for (int r = 0; r < 4; r++) {
      float sv = sa[cb][r] * 0.125f;
      if (need_mask && (cb * 16 + r > thr)) sv = -3.0e38f;
      sa[cb][r] = sv;
      mx = fmaxf(mx, sv);
    }
  mx = fmaxf(mx, __shfl_xor(mx, 16));
  mx = fmaxf(mx, __shfl_xor(mx, 32));
  const float mnew = fmaxf(st.m, mx);
  const float alpha = __expf(st.m - mnew);
  st.m = mnew;
  float rsum = 0.f;
  #pragma unroll
  for (int cb = 0; cb < 4; cb++) {
    u16x4 pw;
    #pragma unroll
    for (int r = 0; r < 4; r++) {
      const float p = __expf(sa[cb][r] - mnew);
      rsum += p;
      pw[r] = f2bf(p);
    }
    *(u16x4*)&Pw[l15 * 64 + ((cb * 16 + l4 * 4) ^ ((l15 & 7) << 3))] = pw;
  }
  rsum += __shfl_xor(rsum, 16);
  rsum += __shfl_xor(rsum, 32);
  st.l = st.l * alpha + rsum;
  #pragma unroll
  for (int r = 0; r < 4; r++) {
    const float ar = __shfl(alpha, l4 * 4 + r);
    #pragma unroll
    for (int cb = 0; cb < 4; cb++) st.o[cb][r] *= ar;
  }
  asm volatile("s_waitcnt lgkmcnt(0)" ::: "memory");
  __builtin_amdgcn_s_setprio(1);
  #pragma unroll
  for (int ks = 0; ks < 2; ++ks) {
    s16x8 pa = *(const s16x8*)&Pw[l15 * 64 + ((ks * 32 + l4 * 8) ^ ((l15 & 7) << 3))];
    #pragma unroll
    for (int cb = 0; cb < 4; cb++) {
      const int d = cb * 16 + l15;
      s16x8 vf = *(const s16x8*)&Vt[d * 64 + ((ks * 32 + l4 * 8) ^ (((d >> 2) & 7) << 3))];
      st.o[cb] = __builtin_amdgcn_mfma_f32_16x16x32_bf16(pa, vf, st.o[cb], 0, 0, 0);
    }
  }
  __builtin_amdgcn_s_setprio(0);
}

DEV void attn_write(unsigned short* orow, const AttnState& st, int l15, int l4) {
  const float invl = 1.0f / st.l;
  #pragma unroll
  for (int r = 0; r < 4; r++) {
    const float ir = __shfl(invl, l4 * 4 + r);
    #pragma unroll
    for (int cb = 0; cb < 4; cb++)
      orow[(l4 * 4 + r) * 1024 + cb * 16 + l15] = f2bf(st.o[cb][r] * ir);
  }
}

__global__ __launch_bounds__(256) void attn_kernel(
    const unsigned short* __restrict__ qkv, unsigned short* __restrict__ outb)
{
  __shared__ unsigned short Ks[64 * 64];
  __shared__ unsigned short Vt[64 * 64];
  __shared__ unsigned short Ps[2][4][16 * 64];
  const int pid = blockIdx.x;
  const int qA = pid, qB = 31 - pid;
  const int bh = blockIdx.y;
  const int b = bh >> 4, h = bh & 15;
  const int tid = threadIdx.x, lane = tid & 63, wid = tid >> 6;
  const int l15 = lane & 15, l4 = lane >> 4;
  const size_t base = (size_t)b * 2048 * 3072 + (size_t)h * 64;
  const unsigned short* Qb = qkv + base;
  const unsigned short* Kb = qkv + base + 1024;
  const unsigned short* Vb = qkv + base + 2048;

  s16x8 qfA[2], qfB[2];
  {
    const unsigned short* qr = Qb + (size_t)(qA * 64 + wid * 16 + l15) * 3072 + l4 * 8;
    qfA[0] = *(const s16x8*)qr;
    qfA[1] = *(const s16x8*)(qr + 32);
    qr = Qb + (size_t)(qB * 64 + wid * 16 + l15) * 3072 + l4 * 8;
    qfB[0] = *(const s16x8*)qr;
    qfB[1] = *(const s16x8*)(qr + 32);
  }
  AttnState sA, sB;
  #pragma unroll
  for (int cb = 0; cb < 4; cb++) {
    sA.o[cb] = (f32x4){0.f, 0.f, 0.f, 0.f};
    sB.o[cb] = (f32x4){0.f, 0.f, 0.f, 0.f};
  }
  sA.m = -1e30f; sA.l = 0.f; sB.m = -1e30f; sB.l = 0.f;
  const int qgA = qA * 64 + wid * 16 + l15;
  const int qgB = qB * 64 + wid * 16 + l15;

  for (int kvb = 0; kvb <= qB; ++kvb) {
    const int kv0 = kvb * 64;
    __syncthreads();
    #pragma unroll
    for (int s = 0; s < 2; ++s) {
      const int c = s * 256 + tid;
      const int kv = c >> 3;
      const int dsrc = ((c & 7) * 8) ^ ((kv & 7) << 3);
      gload_lds16(Kb + (size_t)(kv0 + kv) * 3072 + dsrc,
                  Ks + (size_t)(c & ~63) * 8);
    }
    #pragma unroll
    for (int it = 0; it < 4; ++it) {
      const int cc = tid + 256 * it;
      const int vkv = cc >> 4;
      const int vd = (cc & 15) * 4;
      u16x4 vv = *(const u16x4*)(Vb + (size_t)(kv0 + vkv) * 3072 + vd);
      #pragma unroll
      for (int j = 0; j < 4; j++) {
        const int d = vd + j;
        Vt[d * 64 + (vkv ^ (((d >> 2) & 7) << 3))] = vv[j];
      }
    }
    __syncthreads();

    if (kvb <= qA)
      attn_tile(qfA, Ks, Vt, Ps[0][wid], sA, kv0, qgA, l15, l4,
                kv0 + 63 > qA * 64 + wid * 16);
    attn_tile(qfB, Ks, Vt, Ps[1][wid], sB, kv0, qgB, l15, l4,
              kv0 + 63 > qB * 64 + wid * 16);
  }
  attn_write(outb + ((size_t)b * 2048 + qA * 64 + wid * 16) * 1024 + h * 64, sA, l15, l4);
  attn_write(outb + ((size_t)b * 2048 + qB * 64 + wid * 16) * 1024 + h * 64, sB, l15, l4);
}

// ---------------- host ----------------
extern "C" void kernel_launch(void* const* d_in, const int* in_sizes, int n_in,
                              void* d_out, int out_size, void* d_ws, size_t ws_size,
                              hipStream_t stream) {
  const float* x      = (const float*)d_in[0];
  const float* ln1_g  = (const float*)d_in[1];
  const float* ln1_b  = (const float*)d_in[2];
  const float* qkv_w  = (const float*)d_in[3];
  const float* qkv_b  = (const float*)d_in[4];
  const float* proj_w = (const float*)d_in[5];
  const float* proj_b = (const float*)d_in[6];
  const float* ln2_g  = (const float*)d_in[7];
  const float* ln2_b  = (const float*)d_in[8];
  const float* ff1_w  = (const float*)d_in[9];
  const float* ff1_b  = (const float*)d_in[10];
  const float* ff2_w  = (const float*)d_in[11];
  const float* ff2_b  = (const float*)d_in[12];
  float* out = (float*)d_out;

  char* ws = (char*)d_ws;
  size_t off = 0;
  unsigned short* wbuf   = (unsigned short*)(ws + off); off += (size_t)4096 * 1024 * 2;  // 8 MiB
  unsigned short* hbuf   = (unsigned short*)(ws + off); off += (size_t)8192 * 1024 * 2;  // 16 MiB
  unsigned short* qkvbuf = (unsigned short*)(ws + off); off += (size_t)8192 * 3072 * 2;  // 48 MiB
  unsigned short* gbuf   = (unsigned short*)(ws + off);                                   // 64 MiB

  // ---- attention sublayer ----
  ln_kernel<<<8192, 256, 0, stream>>>(x, ln1_g, ln1_b, hbuf);
  transpose_kernel<<<dim3(3072 / 64, 1024 / 64), 256, 0, stream>>>(qkv_w, wbuf, 1024, 3072);
  gemm8_kernel<0><<<dim3(32 * 12), 512, 0, stream>>>(hbuf, wbuf, qkv_b, nullptr, qkvbuf,
                                                     8192, 3072, 1024);
  attn_kernel<<<dim3(16, 64), 256, 0, stream>>>(qkvbuf, hbuf);
  transpose_kernel<<<dim3(1024 / 64, 1024 / 64), 256, 0, stream>>>(proj_w, wbuf, 1024, 1024);
  gemm_kernel<1><<<dim3(64 * 8), 256, 0, stream>>>(hbuf, wbuf, proj_b, x, out,
                                                   8192, 1024, 1024);   // x1 -> d_out (f32)
  // ---- MLP sublayer ----
  ln_kernel<<<8192, 256, 0, stream>>>(out, ln2_g, ln2_b, hbuf);
  transpose_kernel<<<dim3(4096 / 64, 1024 / 64), 256, 0, stream>>>(ff1_w, wbuf, 1024, 4096);
  gemm8_kernel<2><<<dim3(32 * 16), 512, 0, stream>>>(hbuf, wbuf, ff1_b, nullptr, gbuf,
                                                     8192, 4096, 1024);  // gelu
  transpose_kernel<<<dim3(1024 / 64, 4096 / 64), 256, 0, stream>>>(ff2_w, wbuf, 4096, 1024);
  gemm_kernel<1><<<dim3(64 * 8), 256, 0, stream>>>(gbuf, wbuf, ff2_b, out, out,
                                                   8192, 1024, 4096);   // + x1 in-place
}

// Round 4
// 471.200 us; speedup vs baseline: 1.4564x; 1.0938x over previous
//
#include <hip/hip_runtime.h>

typedef __attribute__((ext_vector_type(4))) float f32x4;
typedef __attribute__((ext_vector_type(8))) short s16x8;
typedef __attribute__((ext_vector_type(4))) unsigned short u16x4;

#define DEV __device__ __forceinline__

DEV unsigned short f2bf(float f) {
  unsigned int u = __float_as_uint(f);
  return (unsigned short)((u + 0x7FFFu + ((u >> 16) & 1u)) >> 16);
}

DEV void gload_lds16(const void* g, void* l) {
  __builtin_amdgcn_global_load_lds(
      (const __attribute__((address_space(1))) unsigned int*)g,
      (__attribute__((address_space(3))) unsigned int*)l, 16, 0, 0);
}

// ---------------- LayerNorm: fp32 in -> bf16 out (rows of 1024) ----------------
__global__ __launch_bounds__(256) void ln_kernel(
    const float* __restrict__ x, const float* __restrict__ gam,
    const float* __restrict__ bet, unsigned short* __restrict__ o)
{
  const int row = blockIdx.x;
  const int tid = threadIdx.x;
  f32x4 v = *(const f32x4*)(x + (size_t)row * 1024 + tid * 4);
  float s = v[0] + v[1] + v[2] + v[3];
  float s2 = v[0]*v[0] + v[1]*v[1] + v[2]*v[2] + v[3]*v[3];
  #pragma unroll
  for (int m = 1; m < 64; m <<= 1) { s += __shfl_xor(s, m); s2 += __shfl_xor(s2, m); }
  __shared__ float ps[4], ps2[4];
  const int wid = tid >> 6, lane = tid & 63;
  if (lane == 0) { ps[wid] = s; ps2[wid] = s2; }
  __syncthreads();
  s = ps[0] + ps[1] + ps[2] + ps[3];
  s2 = ps2[0] + ps2[1] + ps2[2] + ps2[3];
  const float mu = s * (1.0f / 1024.0f);
  const float rstd = rsqrtf(s2 * (1.0f / 1024.0f) - mu * mu + 1e-5f);
  f32x4 g4 = *(const f32x4*)(gam + tid * 4);
  f32x4 b4 = *(const f32x4*)(bet + tid * 4);
  u16x4 ov;
  #pragma unroll
  for (int j = 0; j < 4; j++) ov[j] = f2bf((v[j] - mu) * rstd * g4[j] + b4[j]);
  *(u16x4*)(o + (size_t)row * 1024 + tid * 4) = ov;
}

// -------- transpose+convert: W[K][N] f32 -> WT[N][K] bf16 (64x64 LDS tiles) --------
__global__ __launch_bounds__(256) void transpose_kernel(
    const float* __restrict__ W, unsigned short* __restrict__ WT, int K, int N)
{
  __shared__ float tile[64][65];
  const int n0 = blockIdx.x * 64, k0 = blockIdx.y * 64;
  const int c = threadIdx.x & 63, r0 = threadIdx.x >> 6;
  #pragma unroll
  for (int r = r0; r < 64; r += 4)
    tile[r][c] = W[(size_t)(k0 + r) * N + n0 + c];
  __syncthreads();
  #pragma unroll
  for (int r = r0; r < 64; r += 4)
    WT[(size_t)(n0 + r) * K + k0 + c] = f2bf(tile[c][r]);
}

// ------- 128x256 GEMM, BK=64, XOR-swizzled LDS, 3-slot ring, counted vmcnt -------
// 8 waves (2M x 4N), per-wave C = 64x64 (4x4 16x16 frags). 2 phases/K-tile,
// 16 MFMA each. Swizzle: chunk c' = c ^ (row&7) (16B chunks, 128B rows) ->
// ds_read_b128 is 2-way bank-aliased (free). Staging: linear LDS dest +
// inverse-swizzled global source (rule 21; involution). 3-slot ring (144KB):
// stage t+2 during tile t; boundary vmcnt(6) keeps 6 loads in flight (T4).
// MODE 0: out bf16; MODE 1: out f32 = v + resid; MODE 2: out bf16 = gelu(v)
template <int MODE>
__global__ __launch_bounds__(512) void gemm8_kernel(
    const unsigned short* __restrict__ A, const unsigned short* __restrict__ WT,
    const float* __restrict__ bias, const float* resid, void* outp,
    int M, int N, int K)
{
  __shared__ unsigned short lds[3 * 24576];   // slot: A 128x64 (16KB) + B 256x64 (32KB)
  const int tid = threadIdx.x;
  const int lane = tid & 63, wid = tid >> 6;
  const int l15 = lane & 15, l4 = lane >> 4;
  const int wm = wid >> 2, wn = wid & 3;
  const int tiles_n = N >> 8;
  const int cpx = gridDim.x >> 3;
  const int id = (blockIdx.x & 7) * cpx + (blockIdx.x >> 3);
  const int bm = id / tiles_n, bn = id % tiles_n;
  const int NT = K >> 6;

  // staging source (inverse-swizzled): thread covers chunk g = j*512 + tid
  // -> LDS row g>>3 (j*64 + tid>>3), swz chunk c' = tid&7;
  //    global chunk = c' ^ (row&7) = (tid&7) ^ ((tid>>3)&7)
  const int srow = tid >> 3;
  const int scol = ((tid & 7) ^ (srow & 7)) * 8;
  const unsigned short* Asrc = A  + (size_t)(bm * 128 + srow) * K + scol;
  const unsigned short* Bsrc = WT + (size_t)(bn * 256 + srow) * K + scol;
  const size_t j64 = (size_t)64 * K;
  const int dwave = wid * 1024;               // byte offset of this wave's chunk run

#define STAGE(t_, ss_) do { \
    char* base_ = (char*)lds + (ss_) * 49152 + dwave; \
    const unsigned short* sA_ = Asrc + (size_t)(t_) * 64; \
    const unsigned short* sB_ = Bsrc + (size_t)(t_) * 64; \
    gload_lds16(sA_,            base_); \
    gload_lds16(sA_ + j64,      base_ + 8192); \
    gload_lds16(sB_,            base_ + 16384); \
    gload_lds16(sB_ + j64,      base_ + 16384 + 8192); \
    gload_lds16(sB_ + 2 * j64,  base_ + 16384 + 16384); \
    gload_lds16(sB_ + 3 * j64,  base_ + 16384 + 24576); \
  } while (0)

  f32x4 acc[4][4] = {};

  // fragment read offsets (shorts, within slot): row*64 + (c ^ (row&7))*8
  // A row = wm*64 + mf*16 + l15 ; B row = wn*64 + nf*16 + l15 ; c = ks*4 + l4
  const int arow0 = wm * 64 + l15;
  const int brow0 = wn * 64 + l15;
  const int cswz = l15 & 7;

  // prologue: stage tiles 0,1 (12 loads in flight); wait tile 0 (oldest 6)
  STAGE(0, 0);
  STAGE(1, 1);
  asm volatile("s_waitcnt vmcnt(6)" ::: "memory");
  __builtin_amdgcn_s_barrier();

  int cs = 0, ss = 2;                          // compute slot t%3, stage slot (t+2)%3
  for (int t = 0; t < NT; ++t) {
    const unsigned short* sa = lds + cs * 24576;
    const unsigned short* sb = sa + 8192;
    s16x8 bf[4][2];
    #pragma unroll
    for (int p = 0; p < 2; ++p) {
      s16x8 af[2][2];
      #pragma unroll
      for (int mi = 0; mi < 2; ++mi)
        #pragma unroll
        for (int ks = 0; ks < 2; ++ks) {
          const int row = arow0 + (p * 2 + mi) * 16;
          af[mi][ks] = *(const s16x8*)&sa[row * 64 + (((ks * 4 + l4) ^ cswz) * 8)];
        }
      if (p == 0) {
        #pragma unroll
        for (int nf = 0; nf < 4; ++nf)
          #pragma unroll
          for (int ks = 0; ks < 2; ++ks) {
            const int row = brow0 + nf * 16;
            bf[nf][ks] = *(const s16x8*)&sb[row * 64 + (((ks * 4 + l4) ^ cswz) * 8)];
          }
        if (t + 2 < NT) STAGE(t + 2, ss);
      }
      __builtin_amdgcn_s_barrier();
      asm volatile("s_waitcnt lgkmcnt(0)" ::: "memory");
      __builtin_amdgcn_sched_barrier(0);
      __builtin_amdgcn_s_setprio(1);
      #pragma unroll
      for (int mi = 0; mi < 2; ++mi)
        #pragma unroll
        for (int nf = 0; nf < 4; ++nf)
          #pragma unroll
          for (int ks = 0; ks < 2; ++ks)
            acc[p * 2 + mi][nf] = __builtin_amdgcn_mfma_f32_16x16x32_bf16(
                af[mi][ks], bf[nf][ks], acc[p * 2 + mi][nf], 0, 0, 0);
      __builtin_amdgcn_s_setprio(0);
      if (p == 1) {
        if (t + 2 < NT)      { asm volatile("s_waitcnt vmcnt(6)" ::: "memory"); }
        else if (t + 1 < NT) { asm volatile("s_waitcnt vmcnt(0)" ::: "memory"); }
      }
      __builtin_amdgcn_s_barrier();
    }
    cs = (cs == 2) ? 0 : cs + 1;
    ss = (ss == 2) ? 0 : ss + 1;
  }
#undef STAGE

  #pragma unroll
  for (int nf = 0; nf < 4; nf++) {
    const int col = bn * 256 + wn * 64 + nf * 16 + l15;
    const float bv = bias[col];
    #pragma unroll
    for (int mf = 0; mf < 4; mf++) {
      #pragma unroll
      for (int r = 0; r < 4; r++) {
        const int row = bm * 128 + wm * 64 + mf * 16 + l4 * 4 + r;
        const size_t off = (size_t)row * N + col;
        float v = acc[mf][nf][r] + bv;
        if (MODE == 1) {
          ((float*)outp)[off] = v + resid[off];
        } else if (MODE == 2) {
          const float tt = __expf(1.5957691216f * (v + 0.044715f * v * v * v));
          ((unsigned short*)outp)[off] = f2bf(v - v / (tt + 1.0f));
        } else {
          ((unsigned short*)outp)[off] = f2bf(v);
        }
      }
    }
  }
}

// ---------------- causal flash attention (paired tiles + swapped QK^T) ----------------
struct AttnState {
  f32x4 o[4];
  float m, l;
};

DEV void attn_tile(const s16x8* qf, const unsigned short* Ks,
                   const unsigned short* Vt, unsigned short* Pw,
                   AttnState& st, int kv0, int qg, int l15, int l4, bool need_mask)
{
  f32x4 sa[4];
  #pragma unroll
  for (int cb = 0; cb < 4; cb++) sa[cb] = (f32x4){0.f, 0.f, 0.f, 0.f};
  __builtin_amdgcn_s_setprio(1);
  #pragma unroll
  for (int ks = 0; ks < 2; ++ks) {
    #pragma unroll
    for (int cb = 0; cb < 4; cb++) {
      const int kvr = cb * 16 + l15;
      s16x8 bk = *(const s16x8*)&Ks[kvr * 64 + ((ks * 32 + l4 * 8) ^ ((kvr & 7) << 3))];
      sa[cb] = __builtin_amdgcn_mfma_f32_16x16x32_bf16(bk, qf[ks], sa[cb], 0, 0, 0);
    }
  }
  __builtin_amdgcn_s_setprio(0);
  float mx = -3.0e38f;
  const int thr = qg - kv0 - l4 * 4;
  #pragma unroll
  for (int cb = 0; cb < 4; cb++)
    #pragma unroll
    for (int r = 0; r < 4; r++) {
      float sv = sa[cb][r] * 0.125f;
      if (need_mask && (cb * 16 + r > thr)) sv = -3.0e38f;
      sa[cb][r] = sv;
      mx = fmaxf(mx, sv);
    }
  mx = fmaxf(mx, __shfl_xor(mx, 16));
  mx = fmaxf(mx, __shfl_xor(mx, 32));
  const float mnew = fmaxf(st.m, mx);
  const float alpha = __expf(st.m - mnew);
  st.m = mnew;
  float rsum = 0.f;
  #pragma unroll
  for (int cb = 0; cb < 4; cb++) {
    u16x4 pw;
    #pragma unroll
    for (int r = 0; r < 4; r++) {
      const float p = __expf(sa[cb][r] - mnew);
      rsum += p;
      pw[r] = f2bf(p);
    }
    *(u16x4*)&Pw[l15 * 64 + ((cb * 16 + l4 * 4) ^ ((l15 & 7) << 3))] = pw;
  }
  rsum += __shfl_xor(rsum, 16);
  rsum += __shfl_xor(rsum, 32);
  st.l = st.l * alpha + rsum;
  #pragma unroll
  for (int r = 0; r < 4; r++) {
    const float ar = __shfl(alpha, l4 * 4 + r);
    #pragma unroll
    for (int cb = 0; cb < 4; cb++) st.o[cb][r] *= ar;
  }
  asm volatile("s_waitcnt lgkmcnt(0)" ::: "memory");
  __builtin_amdgcn_s_setprio(1);
  #pragma unroll
  for (int ks = 0; ks < 2; ++ks) {
    s16x8 pa = *(const s16x8*)&Pw[l15 * 64 + ((ks * 32 + l4 * 8) ^ ((l15 & 7) << 3))];
    #pragma unroll
    for (int cb = 0; cb < 4; cb++) {
      const int d = cb * 16 + l15;
      s16x8 vf = *(const s16x8*)&Vt[d * 64 + ((ks * 32 + l4 * 8) ^ (((d >> 2) & 7) << 3))];
      st.o[cb] = __builtin_amdgcn_mfma_f32_16x16x32_bf16(pa, vf, st.o[cb], 0, 0, 0);
    }
  }
  __builtin_amdgcn_s_setprio(0);
}

DEV void attn_write(unsigned short* orow, const AttnState& st, int l15, int l4) {
  const float invl = 1.0f / st.l;
  #pragma unroll
  for (int r = 0; r < 4; r++) {
    const float ir = __shfl(invl, l4 * 4 + r);
    #pragma unroll
    for (int cb = 0; cb < 4; cb++)
      orow[(l4 * 4 + r) * 1024 + cb * 16 + l15] = f2bf(st.o[cb][r] * ir);
  }
}

__global__ __launch_bounds__(256) void attn_kernel(
    const unsigned short* __restrict__ qkv, unsigned short* __restrict__ outb)
{
  __shared__ unsigned short Ks[64 * 64];
  __shared__ unsigned short Vt[64 * 64];
  __shared__ unsigned short Ps[2][4][16 * 64];
  const int pid = blockIdx.x;
  const int qA = pid, qB = 31 - pid;
  const int bh = blockIdx.y;
  const int b = bh >> 4, h = bh & 15;
  const int tid = threadIdx.x, lane = tid & 63, wid = tid >> 6;
  const int l15 = lane & 15, l4 = lane >> 4;
  const size_t base = (size_t)b * 2048 * 3072 + (size_t)h * 64;
  const unsigned short* Qb = qkv + base;
  const unsigned short* Kb = qkv + base + 1024;
  const unsigned short* Vb = qkv + base + 2048;

  s16x8 qfA[2], qfB[2];
  {
    const unsigned short* qr = Qb + (size_t)(qA * 64 + wid * 16 + l15) * 3072 + l4 * 8;
    qfA[0] = *(const s16x8*)qr;
    qfA[1] = *(const s16x8*)(qr + 32);
    qr = Qb + (size_t)(qB * 64 + wid * 16 + l15) * 3072 + l4 * 8;
    qfB[0] = *(const s16x8*)qr;
    qfB[1] = *(const s16x8*)(qr + 32);
  }
  AttnState sA, sB;
  #pragma unroll
  for (int cb = 0; cb < 4; cb++) {
    sA.o[cb] = (f32x4){0.f, 0.f, 0.f, 0.f};
    sB.o[cb] = (f32x4){0.f, 0.f, 0.f, 0.f};
  }
  sA.m = -1e30f; sA.l = 0.f; sB.m = -1e30f; sB.l = 0.f;
  const int qgA = qA * 64 + wid * 16 + l15;
  const int qgB = qB * 64 + wid * 16 + l15;

  for (int kvb = 0; kvb <= qB; ++kvb) {
    const int kv0 = kvb * 64;
    __syncthreads();
    #pragma unroll
    for (int s = 0; s < 2; ++s) {
      const int c = s * 256 + tid;
      const int kv = c >> 3;
      const int dsrc = ((c & 7) * 8) ^ ((kv & 7) << 3);
      gload_lds16(Kb + (size_t)(kv0 + kv) * 3072 + dsrc,
                  Ks + (size_t)(c & ~63) * 8);
    }
    #pragma unroll
    for (int it = 0; it < 4; ++it) {
      const int cc = tid + 256 * it;
      const int vkv = cc >> 4;
      const int vd = (cc & 15) * 4;
      u16x4 vv = *(const u16x4*)(Vb + (size_t)(kv0 + vkv) * 3072 + vd);
      #pragma unroll
      for (int j = 0; j < 4; j++) {
        const int d = vd + j;
        Vt[d * 64 + (vkv ^ (((d >> 2) & 7) << 3))] = vv[j];
      }
    }
    __syncthreads();

    if (kvb <= qA)
      attn_tile(qfA, Ks, Vt, Ps[0][wid], sA, kv0, qgA, l15, l4,
                kv0 + 63 > qA * 64 + wid * 16);
    attn_tile(qfB, Ks, Vt, Ps[1][wid], sB, kv0, qgB, l15, l4,
              kv0 + 63 > qB * 64 + wid * 16);
  }
  attn_write(outb + ((size_t)b * 2048 + qA * 64 + wid * 16) * 1024 + h * 64, sA, l15, l4);
  attn_write(outb + ((size_t)b * 2048 + qB * 64 + wid * 16) * 1024 + h * 64, sB, l15, l4);
}

// ---------------- host ----------------
extern "C" void kernel_launch(void* const* d_in, const int* in_sizes, int n_in,
                              void* d_out, int out_size, void* d_ws, size_t ws_size,
                              hipStream_t stream) {
  const float* x      = (const float*)d_in[0];
  const float* ln1_g  = (const float*)d_in[1];
  const float* ln1_b  = (const float*)d_in[2];
  const float* qkv_w  = (const float*)d_in[3];
  const float* qkv_b  = (const float*)d_in[4];
  const float* proj_w = (const float*)d_in[5];
  const float* proj_b = (const float*)d_in[6];
  const float* ln2_g  = (const float*)d_in[7];
  const float* ln2_b  = (const float*)d_in[8];
  const float* ff1_w  = (const float*)d_in[9];
  const float* ff1_b  = (const float*)d_in[10];
  const float* ff2_w  = (const float*)d_in[11];
  const float* ff2_b  = (const float*)d_in[12];
  float* out = (float*)d_out;

  char* ws = (char*)d_ws;
  size_t off = 0;
  unsigned short* wbuf   = (unsigned short*)(ws + off); off += (size_t)4096 * 1024 * 2;  // 8 MiB
  unsigned short* hbuf   = (unsigned short*)(ws + off); off += (size_t)8192 * 1024 * 2;  // 16 MiB
  unsigned short* qkvbuf = (unsigned short*)(ws + off); off += (size_t)8192 * 3072 * 2;  // 48 MiB
  unsigned short* gbuf   = (unsigned short*)(ws + off);                                   // 64 MiB

  // ---- attention sublayer ----
  ln_kernel<<<8192, 256, 0, stream>>>(x, ln1_g, ln1_b, hbuf);
  transpose_kernel<<<dim3(3072 / 64, 1024 / 64), 256, 0, stream>>>(qkv_w, wbuf, 1024, 3072);
  gemm8_kernel<0><<<dim3(64 * 12), 512, 0, stream>>>(hbuf, wbuf, qkv_b, nullptr, qkvbuf,
                                                     8192, 3072, 1024);
  attn_kernel<<<dim3(16, 64), 256, 0, stream>>>(qkvbuf, hbuf);
  transpose_kernel<<<dim3(1024 / 64, 1024 / 64), 256, 0, stream>>>(proj_w, wbuf, 1024, 1024);
  gemm8_kernel<1><<<dim3(64 * 4), 512, 0, stream>>>(hbuf, wbuf, proj_b, x, out,
                                                    8192, 1024, 1024);   // x1 -> d_out (f32)
  // ---- MLP sublayer ----
  ln_kernel<<<8192, 256, 0, stream>>>(out, ln2_g, ln2_b, hbuf);
  transpose_kernel<<<dim3(4096 / 64, 1024 / 64), 256, 0, stream>>>(ff1_w, wbuf, 1024, 4096);
  gemm8_kernel<2><<<dim3(64 * 16), 512, 0, stream>>>(hbuf, wbuf, ff1_b, nullptr, gbuf,
                                                     8192, 4096, 1024);  // gelu
  transpose_kernel<<<dim3(1024 / 64, 4096 / 64), 256, 0, stream>>>(ff2_w, wbuf, 4096, 1024);
  gemm8_kernel<1><<<dim3(64 * 4), 512, 0, stream>>>(gbuf, wbuf, ff2_b, out, out,
                                                    8192, 1024, 4096);   // + x1 in-place
}

// Round 5
// 459.524 us; speedup vs baseline: 1.4934x; 1.0254x over previous
//
#include <hip/hip_runtime.h>

typedef __attribute__((ext_vector_type(4))) float f32x4;
typedef __attribute__((ext_vector_type(8))) short s16x8;
typedef __attribute__((ext_vector_type(4))) unsigned short u16x4;

#define DEV __device__ __forceinline__

DEV unsigned short f2bf(float f) {
  unsigned int u = __float_as_uint(f);
  return (unsigned short)((u + 0x7FFFu + ((u >> 16) & 1u)) >> 16);
}

DEV float exp2_asm(float x) {        // v_exp_f32: D = 2^S0
  float r; asm("v_exp_f32 %0, %1" : "=v"(r) : "v"(x)); return r;
}
DEV float rcp_asm(float x) {
  float r; asm("v_rcp_f32 %0, %1" : "=v"(r) : "v"(x)); return r;
}

DEV void gload_lds16(const void* g, void* l) {
  __builtin_amdgcn_global_load_lds(
      (const __attribute__((address_space(1))) unsigned int*)g,
      (__attribute__((address_space(3))) unsigned int*)l, 16, 0, 0);
}

// ---------------- LayerNorm: fp32 in -> bf16 out (rows of 1024) ----------------
__global__ __launch_bounds__(256) void ln_kernel(
    const float* __restrict__ x, const float* __restrict__ gam,
    const float* __restrict__ bet, unsigned short* __restrict__ o)
{
  const int row = blockIdx.x;
  const int tid = threadIdx.x;
  f32x4 v = *(const f32x4*)(x + (size_t)row * 1024 + tid * 4);
  float s = v[0] + v[1] + v[2] + v[3];
  float s2 = v[0]*v[0] + v[1]*v[1] + v[2]*v[2] + v[3]*v[3];
  #pragma unroll
  for (int m = 1; m < 64; m <<= 1) { s += __shfl_xor(s, m); s2 += __shfl_xor(s2, m); }
  __shared__ float ps[4], ps2[4];
  const int wid = tid >> 6, lane = tid & 63;
  if (lane == 0) { ps[wid] = s; ps2[wid] = s2; }
  __syncthreads();
  s = ps[0] + ps[1] + ps[2] + ps[3];
  s2 = ps2[0] + ps2[1] + ps2[2] + ps2[3];
  const float mu = s * (1.0f / 1024.0f);
  const float rstd = rsqrtf(s2 * (1.0f / 1024.0f) - mu * mu + 1e-5f);
  f32x4 g4 = *(const f32x4*)(gam + tid * 4);
  f32x4 b4 = *(const f32x4*)(bet + tid * 4);
  u16x4 ov;
  #pragma unroll
  for (int j = 0; j < 4; j++) ov[j] = f2bf((v[j] - mu) * rstd * g4[j] + b4[j]);
  *(u16x4*)(o + (size_t)row * 1024 + tid * 4) = ov;
}

// -------- transpose+convert: W[K][N] f32 -> WT[N][K] bf16 (64x64 LDS tiles) --------
__global__ __launch_bounds__(256) void transpose_kernel(
    const float* __restrict__ W, unsigned short* __restrict__ WT, int K, int N)
{
  __shared__ float tile[64][65];
  const int n0 = blockIdx.x * 64, k0 = blockIdx.y * 64;
  const int c = threadIdx.x & 63, r0 = threadIdx.x >> 6;
  #pragma unroll
  for (int r = r0; r < 64; r += 4)
    tile[r][c] = W[(size_t)(k0 + r) * N + n0 + c];
  __syncthreads();
  #pragma unroll
  for (int r = r0; r < 64; r += 4)
    WT[(size_t)(n0 + r) * K + k0 + c] = f2bf(tile[c][r]);
}

// ------- 128x256 GEMM, BK=64, XOR-swizzled LDS, 3-slot ring, counted vmcnt -------
// MODE 0: out bf16; MODE 1: out f32 = v + resid; MODE 2: out bf16 = gelu(v)
template <int MODE>
__global__ __launch_bounds__(512) void gemm8_kernel(
    const unsigned short* __restrict__ A, const unsigned short* __restrict__ WT,
    const float* __restrict__ bias, const float* resid, void* outp,
    int M, int N, int K)
{
  __shared__ unsigned short lds[3 * 24576];   // slot: A 128x64 (16KB) + B 256x64 (32KB)
  const int tid = threadIdx.x;
  const int lane = tid & 63, wid = tid >> 6;
  const int l15 = lane & 15, l4 = lane >> 4;
  const int wm = wid >> 2, wn = wid & 3;
  const int tiles_n = N >> 8;
  const int cpx = gridDim.x >> 3;
  const int id = (blockIdx.x & 7) * cpx + (blockIdx.x >> 3);
  const int bm = id / tiles_n, bn = id % tiles_n;
  const int NT = K >> 6;

  const int srow = tid >> 3;
  const int scol = ((tid & 7) ^ (srow & 7)) * 8;
  const unsigned short* Asrc = A  + (size_t)(bm * 128 + srow) * K + scol;
  const unsigned short* Bsrc = WT + (size_t)(bn * 256 + srow) * K + scol;
  const size_t j64 = (size_t)64 * K;
  const int dwave = wid * 1024;

#define STAGE(t_, ss_) do { \
    char* base_ = (char*)lds + (ss_) * 49152 + dwave; \
    const unsigned short* sA_ = Asrc + (size_t)(t_) * 64; \
    const unsigned short* sB_ = Bsrc + (size_t)(t_) * 64; \
    gload_lds16(sA_,            base_); \
    gload_lds16(sA_ + j64,      base_ + 8192); \
    gload_lds16(sB_,            base_ + 16384); \
    gload_lds16(sB_ + j64,      base_ + 16384 + 8192); \
    gload_lds16(sB_ + 2 * j64,  base_ + 16384 + 16384); \
    gload_lds16(sB_ + 3 * j64,  base_ + 16384 + 24576); \
  } while (0)

  f32x4 acc[4][4] = {};

  const int arow0 = wm * 64 + l15;
  const int brow0 = wn * 64 + l15;
  const int cswz = l15 & 7;

  STAGE(0, 0);
  STAGE(1, 1);
  asm volatile("s_waitcnt vmcnt(6)" ::: "memory");
  __builtin_amdgcn_s_barrier();

  int cs = 0, ss = 2;
  for (int t = 0; t < NT; ++t) {
    const unsigned short* sa = lds + cs * 24576;
    const unsigned short* sb = sa + 8192;
    s16x8 bf[4][2];
    #pragma unroll
    for (int p = 0; p < 2; ++p) {
      s16x8 af[2][2];
      #pragma unroll
      for (int mi = 0; mi < 2; ++mi)
        #pragma unroll
        for (int ks = 0; ks < 2; ++ks) {
          const int row = arow0 + (p * 2 + mi) * 16;
          af[mi][ks] = *(const s16x8*)&sa[row * 64 + (((ks * 4 + l4) ^ cswz) * 8)];
        }
      if (p == 0) {
        #pragma unroll
        for (int nf = 0; nf < 4; ++nf)
          #pragma unroll
          for (int ks = 0; ks < 2; ++ks) {
            const int row = brow0 + nf * 16;
            bf[nf][ks] = *(const s16x8*)&sb[row * 64 + (((ks * 4 + l4) ^ cswz) * 8)];
          }
        if (t + 2 < NT) STAGE(t + 2, ss);
      }
      __builtin_amdgcn_s_barrier();
      asm volatile("s_waitcnt lgkmcnt(0)" ::: "memory");
      __builtin_amdgcn_sched_barrier(0);
      __builtin_amdgcn_s_setprio(1);
      #pragma unroll
      for (int mi = 0; mi < 2; ++mi)
        #pragma unroll
        for (int nf = 0; nf < 4; ++nf)
          #pragma unroll
          for (int ks = 0; ks < 2; ++ks)
            acc[p * 2 + mi][nf] = __builtin_amdgcn_mfma_f32_16x16x32_bf16(
                af[mi][ks], bf[nf][ks], acc[p * 2 + mi][nf], 0, 0, 0);
      __builtin_amdgcn_s_setprio(0);
      if (p == 1) {
        if (t + 2 < NT)      { asm volatile("s_waitcnt vmcnt(6)" ::: "memory"); }
        else if (t + 1 < NT) { asm volatile("s_waitcnt vmcnt(0)" ::: "memory"); }
      }
      __builtin_amdgcn_s_barrier();
    }
    cs = (cs == 2) ? 0 : cs + 1;
    ss = (ss == 2) ? 0 : ss + 1;
  }
#undef STAGE

  #pragma unroll
  for (int nf = 0; nf < 4; nf++) {
    const int col = bn * 256 + wn * 64 + nf * 16 + l15;
    const float bv = bias[col];
    #pragma unroll
    for (int mf = 0; mf < 4; mf++) {
      #pragma unroll
      for (int r = 0; r < 4; r++) {
        const int row = bm * 128 + wm * 64 + mf * 16 + l4 * 4 + r;
        const size_t off = (size_t)row * N + col;
        float v = acc[mf][nf][r] + bv;
        if (MODE == 1) {
          ((float*)outp)[off] = v + resid[off];
        } else if (MODE == 2) {
          // gelu(v) = v * sigmoid(1.59577*(v+0.044715 v^3)); exp2/rcp fast path
          const float u = v + 0.044715f * v * v * v;
          const float e = exp2_asm(-2.3022010f * u);
          ((unsigned short*)outp)[off] = f2bf(v * rcp_asm(1.0f + e));
        } else {
          ((unsigned short*)outp)[off] = f2bf(v);
        }
      }
    }
  }
}

// ---------------- causal flash attention ----------------
// Paired q-tiles (qA=pid, qB=31-pid), swapped QK^T, log2-domain softmax with
// defer-max (T13), async K/V prefetch with raw barriers + counted vmcnt (T14).
// LDS: Ks[2] double-buffered (gload_lds, pre-swizzled source), Vt single
// (reg-staged transposed; writes of tile i+1 protected by barrier #1),
// Ps per-wave P round-trip.
struct AttnState {
  f32x4 o[4];
  float m, l;
};

DEV void attn_tile(const s16x8* qf, const unsigned short* Ks,
                   const unsigned short* Vt, unsigned short* Pw,
                   AttnState& st, int kv0, int qg, int l15, int l4, bool need_mask)
{
  f32x4 sa[4];
  #pragma unroll
  for (int cb = 0; cb < 4; cb++) sa[cb] = (f32x4){0.f, 0.f, 0.f, 0.f};
  __builtin_amdgcn_s_setprio(1);
  #pragma unroll
  for (int ks = 0; ks < 2; ++ks) {
    #pragma unroll
    for (int cb = 0; cb < 4; cb++) {
      const int kvr = cb * 16 + l15;
      s16x8 bk = *(const s16x8*)&Ks[kvr * 64 + ((ks * 32 + l4 * 8) ^ ((kvr & 7) << 3))];
      sa[cb] = __builtin_amdgcn_mfma_f32_16x16x32_bf16(bk, qf[ks], sa[cb], 0, 0, 0);
    }
  }
  __builtin_amdgcn_s_setprio(0);
  // log2-domain masked scale + in-lane max (all 16 values belong to q = l15)
  float mx = -3.0e38f;
  const int thr = qg - kv0 - l4 * 4;
  #pragma unroll
  for (int cb = 0; cb < 4; cb++)
    #pragma unroll
    for (int r = 0; r < 4; r++) {
      float sv = sa[cb][r] * 0.18033688f;        // 0.125 * log2(e)
      if (need_mask && (cb * 16 + r > thr)) sv = -3.0e38f;
      sa[cb][r] = sv;
      mx = fmaxf(mx, sv);
    }
  mx = fmaxf(mx, __shfl_xor(mx, 16));
  mx = fmaxf(mx, __shfl_xor(mx, 32));
  const bool skip = __all(mx <= st.m + 11.5f);   // defer-max: P bounded by 2^11.5
  const float mnew = skip ? st.m : fmaxf(st.m, mx);
  float rsum = 0.f;
  #pragma unroll
  for (int cb = 0; cb < 4; cb++) {
    u16x4 pw;
    #pragma unroll
    for (int r = 0; r < 4; r++) {
      const float p = exp2_asm(sa[cb][r] - mnew);
      rsum += p;
      pw[r] = f2bf(p);
    }
    *(u16x4*)&Pw[l15 * 64 + ((cb * 16 + l4 * 4) ^ ((l15 & 7) << 3))] = pw;
  }
  rsum += __shfl_xor(rsum, 16);
  rsum += __shfl_xor(rsum, 32);
  if (skip) {
    st.l += rsum;
  } else {
    const float alpha = exp2_asm(st.m - mnew);
    st.l = st.l * alpha + rsum;
    st.m = mnew;
    #pragma unroll
    for (int r = 0; r < 4; r++) {
      const float ar = __shfl(alpha, l4 * 4 + r);
      #pragma unroll
      for (int cb = 0; cb < 4; cb++) st.o[cb][r] *= ar;
    }
  }
  asm volatile("s_waitcnt lgkmcnt(0)" ::: "memory");  // P writes visible to own wave
  __builtin_amdgcn_s_setprio(1);
  #pragma unroll
  for (int ks = 0; ks < 2; ++ks) {
    s16x8 pa = *(const s16x8*)&Pw[l15 * 64 + ((ks * 32 + l4 * 8) ^ ((l15 & 7) << 3))];
    #pragma unroll
    for (int cb = 0; cb < 4; cb++) {
      const int d = cb * 16 + l15;
      s16x8 vf = *(const s16x8*)&Vt[d * 64 + ((ks * 32 + l4 * 8) ^ (((d >> 2) & 7) << 3))];
      st.o[cb] = __builtin_amdgcn_mfma_f32_16x16x32_bf16(pa, vf, st.o[cb], 0, 0, 0);
    }
  }
  __builtin_amdgcn_s_setprio(0);
}

DEV void attn_write(unsigned short* orow, const AttnState& st, int l15, int l4) {
  const float invl = rcp_asm(st.l);
  #pragma unroll
  for (int r = 0; r < 4; r++) {
    const float ir = __shfl(invl, l4 * 4 + r);
    #pragma unroll
    for (int cb = 0; cb < 4; cb++)
      orow[(l4 * 4 + r) * 1024 + cb * 16 + l15] = f2bf(st.o[cb][r] * ir);
  }
}

__global__ __launch_bounds__(256) void attn_kernel(
    const unsigned short* __restrict__ qkv, unsigned short* __restrict__ outb)
{
  __shared__ unsigned short Ks[2][64 * 64];       // [kv][d^((kv&7)<<3)], double-buffered
  __shared__ unsigned short Vt[64 * 64];          // [d][kv^(((d>>2)&7)<<3)]
  __shared__ unsigned short Ps[2][4][16 * 64];    // per-q-tile, per-wave P
  const int pid = blockIdx.x;                     // 0..15
  const int qA = pid, qB = 31 - pid;
  const int bh = blockIdx.y;
  const int b = bh >> 4, h = bh & 15;
  const int tid = threadIdx.x, lane = tid & 63, wid = tid >> 6;
  const int l15 = lane & 15, l4 = lane >> 4;
  const size_t base = (size_t)b * 2048 * 3072 + (size_t)h * 64;
  const unsigned short* Qb = qkv + base;
  const unsigned short* Kb = qkv + base + 1024;
  const unsigned short* Vb = qkv + base + 2048;

  // Q fragments (4 global loads)
  s16x8 qfA[2], qfB[2];
  {
    const unsigned short* qr = Qb + (size_t)(qA * 64 + wid * 16 + l15) * 3072 + l4 * 8;
    qfA[0] = *(const s16x8*)qr;
    qfA[1] = *(const s16x8*)(qr + 32);
    qr = Qb + (size_t)(qB * 64 + wid * 16 + l15) * 3072 + l4 * 8;
    qfB[0] = *(const s16x8*)qr;
    qfB[1] = *(const s16x8*)(qr + 32);
  }

  // prologue: V(0) reg loads FIRST, then K(0) gload_lds (vmcnt counts rely on order)
  u16x4 vv[4];
  #pragma unroll
  for (int it = 0; it < 4; ++it) {
    const int cc = tid + 256 * it;
    vv[it] = *(const u16x4*)(Vb + (size_t)(cc >> 4) * 3072 + (cc & 15) * 4);
  }
  #pragma unroll
  for (int s = 0; s < 2; ++s) {
    const int c = s * 256 + tid;
    const int kv = c >> 3;
    const int dsrc = ((c & 7) * 8) ^ ((kv & 7) << 3);
    gload_lds16(Kb + (size_t)kv * 3072 + dsrc, &Ks[0][(size_t)(c & ~63) * 8]);
  }

  AttnState sA, sB;
  #pragma unroll
  for (int cb = 0; cb < 4; cb++) {
    sA.o[cb] = (f32x4){0.f, 0.f, 0.f, 0.f};
    sB.o[cb] = (f32x4){0.f, 0.f, 0.f, 0.f};
  }
  sA.m = -1e30f; sA.l = 0.f; sB.m = -1e30f; sB.l = 0.f;
  const int qgA = qA * 64 + wid * 16 + l15;
  const int qgB = qB * 64 + wid * 16 + l15;

  for (int kvb = 0; kvb <= qB; ++kvb) {
    const int cur = kvb & 1;
    const int kv0 = kvb * 64;
    __builtin_amdgcn_s_barrier();                 // #1: prev tile fully consumed
    asm volatile("s_waitcnt vmcnt(2)" ::: "memory");   // V(kvb) regs landed; K(kvb) flying
    // publish V(kvb): reg -> swizzled Vt
    #pragma unroll
    for (int it = 0; it < 4; ++it) {
      const int cc = tid + 256 * it;
      const int vkv = cc >> 4;
      const int vd = (cc & 15) * 4;
      #pragma unroll
      for (int j = 0; j < 4; j++) {
        const int d = vd + j;
        Vt[d * 64 + (vkv ^ (((d >> 2) & 7) << 3))] = vv[it][j];
      }
    }
    if (kvb < qB) {
      // prefetch V(kvb+1) into regs (stays in flight across compute)
      #pragma unroll
      for (int it = 0; it < 4; ++it) {
        const int cc = tid + 256 * it;
        vv[it] = *(const u16x4*)(Vb + (size_t)((kvb + 1) * 64 + (cc >> 4)) * 3072 + (cc & 15) * 4);
      }
      asm volatile("s_waitcnt vmcnt(4)" ::: "memory");  // K(kvb) landed; V(kvb+1) flying
    } else {
      asm volatile("s_waitcnt vmcnt(0)" ::: "memory");  // last tile: drain K
    }
    asm volatile("s_waitcnt lgkmcnt(0)" ::: "memory");  // Vt ds_writes drained
    __builtin_amdgcn_s_barrier();                 // #2: Ks[cur], Vt published
    if (kvb < qB) {
      // prefetch K(kvb+1) -> Ks[cur^1] (readers of that slot finished pre-#1)
      #pragma unroll
      for (int s = 0; s < 2; ++s) {
        const int c = s * 256 + tid;
        const int kv = c >> 3;
        const int dsrc = ((c & 7) * 8) ^ ((kv & 7) << 3);
        gload_lds16(Kb + (size_t)((kvb + 1) * 64 + kv) * 3072 + dsrc,
                    &Ks[cur ^ 1][(size_t)(c & ~63) * 8]);
      }
    }
    if (kvb <= qA)
      attn_tile(qfA, Ks[cur], Vt, Ps[0][wid], sA, kv0, qgA, l15, l4,
                kv0 + 63 > qA * 64 + wid * 16);
    attn_tile(qfB, Ks[cur], Vt, Ps[1][wid], sB, kv0, qgB, l15, l4,
              kv0 + 63 > qB * 64 + wid * 16);
  }
  attn_write(outb + ((size_t)b * 2048 + qA * 64 + wid * 16) * 1024 + h * 64, sA, l15, l4);
  attn_write(outb + ((size_t)b * 2048 + qB * 64 + wid * 16) * 1024 + h * 64, sB, l15, l4);
}

// ---------------- host ----------------
extern "C" void kernel_launch(void* const* d_in, const int* in_sizes, int n_in,
                              void* d_out, int out_size, void* d_ws, size_t ws_size,
                              hipStream_t stream) {
  const float* x      = (const float*)d_in[0];
  const float* ln1_g  = (const float*)d_in[1];
  const float* ln1_b  = (const float*)d_in[2];
  const float* qkv_w  = (const float*)d_in[3];
  const float* qkv_b  = (const float*)d_in[4];
  const float* proj_w = (const float*)d_in[5];
  const float* proj_b = (const float*)d_in[6];
  const float* ln2_g  = (const float*)d_in[7];
  const float* ln2_b  = (const float*)d_in[8];
  const float* ff1_w  = (const float*)d_in[9];
  const float* ff1_b  = (const float*)d_in[10];
  const float* ff2_w  = (const float*)d_in[11];
  const float* ff2_b  = (const float*)d_in[12];
  float* out = (float*)d_out;

  char* ws = (char*)d_ws;
  size_t off = 0;
  unsigned short* wbuf   = (unsigned short*)(ws + off); off += (size_t)4096 * 1024 * 2;  // 8 MiB
  unsigned short* hbuf   = (unsigned short*)(ws + off); off += (size_t)8192 * 1024 * 2;  // 16 MiB
  unsigned short* qkvbuf = (unsigned short*)(ws + off); off += (size_t)8192 * 3072 * 2;  // 48 MiB
  unsigned short* gbuf   = (unsigned short*)(ws + off);                                   // 64 MiB

  // ---- attention sublayer ----
  ln_kernel<<<8192, 256, 0, stream>>>(x, ln1_g, ln1_b, hbuf);
  transpose_kernel<<<dim3(3072 / 64, 1024 / 64), 256, 0, stream>>>(qkv_w, wbuf, 1024, 3072);
  gemm8_kernel<0><<<dim3(64 * 12), 512, 0, stream>>>(hbuf, wbuf, qkv_b, nullptr, qkvbuf,
                                                     8192, 3072, 1024);
  attn_kernel<<<dim3(16, 64), 256, 0, stream>>>(qkvbuf, hbuf);
  transpose_kernel<<<dim3(1024 / 64, 1024 / 64), 256, 0, stream>>>(proj_w, wbuf, 1024, 1024);
  gemm8_kernel<1><<<dim3(64 * 4), 512, 0, stream>>>(hbuf, wbuf, proj_b, x, out,
                                                    8192, 1024, 1024);   // x1 -> d_out (f32)
  // ---- MLP sublayer ----
  ln_kernel<<<8192, 256, 0, stream>>>(out, ln2_g, ln2_b, hbuf);
  transpose_kernel<<<dim3(4096 / 64, 1024 / 64), 256, 0, stream>>>(ff1_w, wbuf, 1024, 4096);
  gemm8_kernel<2><<<dim3(64 * 16), 512, 0, stream>>>(hbuf, wbuf, ff1_b, nullptr, gbuf,
                                                     8192, 4096, 1024);  // gelu
  transpose_kernel<<<dim3(1024 / 64, 4096 / 64), 256, 0, stream>>>(ff2_w, wbuf, 4096, 1024);
  gemm8_kernel<1><<<dim3(64 * 4), 512, 0, stream>>>(gbuf, wbuf, ff2_b, out, out,
                                                    8192, 1024, 4096);   // + x1 in-place
}

// Round 6
// 455.135 us; speedup vs baseline: 1.5078x; 1.0096x over previous
//
#include <hip/hip_runtime.h>

typedef __attribute__((ext_vector_type(4))) float f32x4;
typedef __attribute__((ext_vector_type(8))) short s16x8;
typedef __attribute__((ext_vector_type(4))) unsigned short u16x4;

#define DEV __device__ __forceinline__

DEV unsigned short f2bf(float f) {
  unsigned int u = __float_as_uint(f);
  return (unsigned short)((u + 0x7FFFu + ((u >> 16) & 1u)) >> 16);
}

DEV float exp2_asm(float x) {        // v_exp_f32: D = 2^S0
  float r; asm("v_exp_f32 %0, %1" : "=v"(r) : "v"(x)); return r;
}
DEV float rcp_asm(float x) {
  float r; asm("v_rcp_f32 %0, %1" : "=v"(r) : "v"(x)); return r;
}

DEV void gload_lds16(const void* g, void* l) {
  __builtin_amdgcn_global_load_lds(
      (const __attribute__((address_space(1))) unsigned int*)g,
      (__attribute__((address_space(3))) unsigned int*)l, 16, 0, 0);
}

// ---------------- LayerNorm: fp32 in -> bf16 out (rows of 1024) ----------------
__global__ __launch_bounds__(256) void ln_kernel(
    const float* __restrict__ x, const float* __restrict__ gam,
    const float* __restrict__ bet, unsigned short* __restrict__ o)
{
  const int row = blockIdx.x;
  const int tid = threadIdx.x;
  f32x4 v = *(const f32x4*)(x + (size_t)row * 1024 + tid * 4);
  float s = v[0] + v[1] + v[2] + v[3];
  float s2 = v[0]*v[0] + v[1]*v[1] + v[2]*v[2] + v[3]*v[3];
  #pragma unroll
  for (int m = 1; m < 64; m <<= 1) { s += __shfl_xor(s, m); s2 += __shfl_xor(s2, m); }
  __shared__ float ps[4], ps2[4];
  const int wid = tid >> 6, lane = tid & 63;
  if (lane == 0) { ps[wid] = s; ps2[wid] = s2; }
  __syncthreads();
  s = ps[0] + ps[1] + ps[2] + ps[3];
  s2 = ps2[0] + ps2[1] + ps2[2] + ps2[3];
  const float mu = s * (1.0f / 1024.0f);
  const float rstd = rsqrtf(s2 * (1.0f / 1024.0f) - mu * mu + 1e-5f);
  f32x4 g4 = *(const f32x4*)(gam + tid * 4);
  f32x4 b4 = *(const f32x4*)(bet + tid * 4);
  u16x4 ov;
  #pragma unroll
  for (int j = 0; j < 4; j++) ov[j] = f2bf((v[j] - mu) * rstd * g4[j] + b4[j]);
  *(u16x4*)(o + (size_t)row * 1024 + tid * 4) = ov;
}

// -------- transpose+convert: W[K][N] f32 -> WT[N][K] bf16 (64x64 LDS tiles) --------
__global__ __launch_bounds__(256) void transpose_kernel(
    const float* __restrict__ W, unsigned short* __restrict__ WT, int K, int N)
{
  __shared__ float tile[64][65];
  const int n0 = blockIdx.x * 64, k0 = blockIdx.y * 64;
  const int c = threadIdx.x & 63, r0 = threadIdx.x >> 6;
  #pragma unroll
  for (int r = r0; r < 64; r += 4)
    tile[r][c] = W[(size_t)(k0 + r) * N + n0 + c];
  __syncthreads();
  #pragma unroll
  for (int r = r0; r < 64; r += 4)
    WT[(size_t)(n0 + r) * K + k0 + c] = f2bf(tile[c][r]);
}

// --- 128x256 GEMM, BK=64, XOR-swizzled LDS, 3-slot ring, ONE barrier/K-tile ---
// Per tile: {ds_read all frags; STAGE(t+2); [compiler counted lgkmcnt]; 32 MFMA;
// counted vmcnt; s_barrier}. Reads of one wave overlap MFMA of others (no
// read/MFMA barrier). Ring safety: STAGE(t+2) hits the slot read at t-1; those
// reads are drained by each wave's own waits before its t-1 trailing barrier.
// vmcnt(6) at tile end retires tile t+1's 6 loads (t+2's 6 stay in flight).
// MODE 0: out bf16; MODE 1: out f32 = v + resid; MODE 2: out bf16 = gelu(v)
template <int MODE>
__global__ __launch_bounds__(512) void gemm8_kernel(
    const unsigned short* __restrict__ A, const unsigned short* __restrict__ WT,
    const float* __restrict__ bias, const float* resid, void* outp,
    int M, int N, int K)
{
  __shared__ unsigned short lds[3 * 24576];   // slot: A 128x64 (16KB) + B 256x64 (32KB)
  const int tid = threadIdx.x;
  const int lane = tid & 63, wid = tid >> 6;
  const int l15 = lane & 15, l4 = lane >> 4;
  const int wm = wid >> 2, wn = wid & 3;
  const int tiles_n = N >> 8;
  const int cpx = gridDim.x >> 3;
  const int id = (blockIdx.x & 7) * cpx + (blockIdx.x >> 3);
  const int bm = id / tiles_n, bn = id % tiles_n;
  const int NT = K >> 6;

  // staging source (inverse-swizzled): LDS row tid>>3, swz chunk tid&7
  const int srow = tid >> 3;
  const int scol = ((tid & 7) ^ (srow & 7)) * 8;
  const unsigned short* Asrc = A  + (size_t)(bm * 128 + srow) * K + scol;
  const unsigned short* Bsrc = WT + (size_t)(bn * 256 + srow) * K + scol;
  const size_t j64 = (size_t)64 * K;
  const int dwave = wid * 1024;

#define STAGE(t_, ss_) do { \
    char* base_ = (char*)lds + (ss_) * 49152 + dwave; \
    const unsigned short* sA_ = Asrc + (size_t)(t_) * 64; \
    const unsigned short* sB_ = Bsrc + (size_t)(t_) * 64; \
    gload_lds16(sA_,            base_); \
    gload_lds16(sA_ + j64,      base_ + 8192); \
    gload_lds16(sB_,            base_ + 16384); \
    gload_lds16(sB_ + j64,      base_ + 16384 + 8192); \
    gload_lds16(sB_ + 2 * j64,  base_ + 16384 + 16384); \
    gload_lds16(sB_ + 3 * j64,  base_ + 16384 + 24576); \
  } while (0)

  f32x4 acc[4][4] = {};

  // fragment read offsets (shorts, within slot): row*64 + ((c ^ (row&7))*8)
  const int arow0 = wm * 64 + l15;
  const int brow0 = wn * 64 + l15;
  const int cswz = l15 & 7;

  STAGE(0, 0);
  STAGE(1, 1);
  asm volatile("s_waitcnt vmcnt(6)" ::: "memory");
  __builtin_amdgcn_s_barrier();

  int cs = 0, ss = 2;
  for (int t = 0; t < NT; ++t) {
    const unsigned short* sa = lds + cs * 24576;
    const unsigned short* sb = sa + 8192;
    s16x8 af[4][2], bf[4][2];
    #pragma unroll
    for (int mf = 0; mf < 4; ++mf)
      #pragma unroll
      for (int ks = 0; ks < 2; ++ks)
        af[mf][ks] = *(const s16x8*)&sa[(arow0 + mf * 16) * 64 + (((ks * 4 + l4) ^ cswz) * 8)];
    #pragma unroll
    for (int nf = 0; nf < 4; ++nf)
      #pragma unroll
      for (int ks = 0; ks < 2; ++ks)
        bf[nf][ks] = *(const s16x8*)&sb[(brow0 + nf * 16) * 64 + (((ks * 4 + l4) ^ cswz) * 8)];
    if (t + 2 < NT) STAGE(t + 2, ss);
    __builtin_amdgcn_s_setprio(1);
    #pragma unroll
    for (int mf = 0; mf < 4; ++mf)
      #pragma unroll
      for (int nf = 0; nf < 4; ++nf)
        #pragma unroll
        for (int ks = 0; ks < 2; ++ks)
          acc[mf][nf] = __builtin_amdgcn_mfma_f32_16x16x32_bf16(
              af[mf][ks], bf[nf][ks], acc[mf][nf], 0, 0, 0);
    __builtin_amdgcn_s_setprio(0);
    if (t + 2 < NT)      { asm volatile("s_waitcnt vmcnt(6)" ::: "memory"); }
    else if (t + 1 < NT) { asm volatile("s_waitcnt vmcnt(0)" ::: "memory"); }
    __builtin_amdgcn_s_barrier();
    cs = (cs == 2) ? 0 : cs + 1;
    ss = (ss == 2) ? 0 : ss + 1;
  }
#undef STAGE

  #pragma unroll
  for (int nf = 0; nf < 4; nf++) {
    const int col = bn * 256 + wn * 64 + nf * 16 + l15;
    const float bv = bias[col];
    #pragma unroll
    for (int mf = 0; mf < 4; mf++) {
      #pragma unroll
      for (int r = 0; r < 4; r++) {
        const int row = bm * 128 + wm * 64 + mf * 16 + l4 * 4 + r;
        const size_t off = (size_t)row * N + col;
        float v = acc[mf][nf][r] + bv;
        if (MODE == 1) {
          ((float*)outp)[off] = v + resid[off];
        } else if (MODE == 2) {
          // gelu(v) = v * sigmoid(1.59577*(v+0.044715 v^3)); exp2/rcp fast path
          const float u = v + 0.044715f * v * v * v;
          const float e = exp2_asm(-2.3022010f * u);
          ((unsigned short*)outp)[off] = f2bf(v * rcp_asm(1.0f + e));
        } else {
          ((unsigned short*)outp)[off] = f2bf(v);
        }
      }
    }
  }
}

// ---------------- causal flash attention (unchanged from R5) ----------------
struct AttnState {
  f32x4 o[4];
  float m, l;
};

DEV void attn_tile(const s16x8* qf, const unsigned short* Ks,
                   const unsigned short* Vt, unsigned short* Pw,
                   AttnState& st, int kv0, int qg, int l15, int l4, bool need_mask)
{
  f32x4 sa[4];
  #pragma unroll
  for (int cb = 0; cb < 4; cb++) sa[cb] = (f32x4){0.f, 0.f, 0.f, 0.f};
  __builtin_amdgcn_s_setprio(1);
  #pragma unroll
  for (int ks = 0; ks < 2; ++ks) {
    #pragma unroll
    for (int cb = 0; cb < 4; cb++) {
      const int kvr = cb * 16 + l15;
      s16x8 bk = *(const s16x8*)&Ks[kvr * 64 + ((ks * 32 + l4 * 8) ^ ((kvr & 7) << 3))];
      sa[cb] = __builtin_amdgcn_mfma_f32_16x16x32_bf16(bk, qf[ks], sa[cb], 0, 0, 0);
    }
  }
  __builtin_amdgcn_s_setprio(0);
  float mx = -3.0e38f;
  const int thr = qg - kv0 - l4 * 4;
  #pragma unroll
  for (int cb = 0; cb < 4; cb++)
    #pragma unroll
    for (int r = 0; r < 4; r++) {
      float sv = sa[cb][r] * 0.18033688f;        // 0.125 * log2(e)
      if (need_mask && (cb * 16 + r > thr)) sv = -3.0e38f;
      sa[cb][r] = sv;
      mx = fmaxf(mx, sv);
    }
  mx = fmaxf(mx, __shfl_xor(mx, 16));
  mx = fmaxf(mx, __shfl_xor(mx, 32));
  const bool skip = __all(mx <= st.m + 11.5f);   // defer-max: P bounded by 2^11.5
  const float mnew = skip ? st.m : fmaxf(st.m, mx);
  float rsum = 0.f;
  #pragma unroll
  for (int cb = 0; cb < 4; cb++) {
    u16x4 pw;
    #pragma unroll
    for (int r = 0; r < 4; r++) {
      const float p = exp2_asm(sa[cb][r] - mnew);
      rsum += p;
      pw[r] = f2bf(p);
    }
    *(u16x4*)&Pw[l15 * 64 + ((cb * 16 + l4 * 4) ^ ((l15 & 7) << 3))] = pw;
  }
  rsum += __shfl_xor(rsum, 16);
  rsum += __shfl_xor(rsum, 32);
  if (skip) {
    st.l += rsum;
  } else {
    const float alpha = exp2_asm(st.m - mnew);
    st.l = st.l * alpha + rsum;
    st.m = mnew;
    #pragma unroll
    for (int r = 0; r < 4; r++) {
      const float ar = __shfl(alpha, l4 * 4 + r);
      #pragma unroll
      for (int cb = 0; cb < 4; cb++) st.o[cb][r] *= ar;
    }
  }
  asm volatile("s_waitcnt lgkmcnt(0)" ::: "memory");  // P writes visible to own wave
  __builtin_amdgcn_s_setprio(1);
  #pragma unroll
  for (int ks = 0; ks < 2; ++ks) {
    s16x8 pa = *(const s16x8*)&Pw[l15 * 64 + ((ks * 32 + l4 * 8) ^ ((l15 & 7) << 3))];
    #pragma unroll
    for (int cb = 0; cb < 4; cb++) {
      const int d = cb * 16 + l15;
      s16x8 vf = *(const s16x8*)&Vt[d * 64 + ((ks * 32 + l4 * 8) ^ (((d >> 2) & 7) << 3))];
      st.o[cb] = __builtin_amdgcn_mfma_f32_16x16x32_bf16(pa, vf, st.o[cb], 0, 0, 0);
    }
  }
  __builtin_amdgcn_s_setprio(0);
}

DEV void attn_write(unsigned short* orow, const AttnState& st, int l15, int l4) {
  const float invl = rcp_asm(st.l);
  #pragma unroll
  for (int r = 0; r < 4; r++) {
    const float ir = __shfl(invl, l4 * 4 + r);
    #pragma unroll
    for (int cb = 0; cb < 4; cb++)
      orow[(l4 * 4 + r) * 1024 + cb * 16 + l15] = f2bf(st.o[cb][r] * ir);
  }
}

__global__ __launch_bounds__(256) void attn_kernel(
    const unsigned short* __restrict__ qkv, unsigned short* __restrict__ outb)
{
  __shared__ unsigned short Ks[2][64 * 64];       // [kv][d^((kv&7)<<3)], double-buffered
  __shared__ unsigned short Vt[64 * 64];          // [d][kv^(((d>>2)&7)<<3)]
  __shared__ unsigned short Ps[2][4][16 * 64];    // per-q-tile, per-wave P
  const int pid = blockIdx.x;                     // 0..15
  const int qA = pid, qB = 31 - pid;
  const int bh = blockIdx.y;
  const int b = bh >> 4, h = bh & 15;
  const int tid = threadIdx.x, lane = tid & 63, wid = tid >> 6;
  const int l15 = lane & 15, l4 = lane >> 4;
  const size_t base = (size_t)b * 2048 * 3072 + (size_t)h * 64;
  const unsigned short* Qb = qkv + base;
  const unsigned short* Kb = qkv + base + 1024;
  const unsigned short* Vb = qkv + base + 2048;

  s16x8 qfA[2], qfB[2];
  {
    const unsigned short* qr = Qb + (size_t)(qA * 64 + wid * 16 + l15) * 3072 + l4 * 8;
    qfA[0] = *(const s16x8*)qr;
    qfA[1] = *(const s16x8*)(qr + 32);
    qr = Qb + (size_t)(qB * 64 + wid * 16 + l15) * 3072 + l4 * 8;
    qfB[0] = *(const s16x8*)qr;
    qfB[1] = *(const s16x8*)(qr + 32);
  }

  // prologue: V(0) reg loads FIRST, then K(0) gload_lds (vmcnt counts rely on order)
  u16x4 vv[4];
  #pragma unroll
  for (int it = 0; it < 4; ++it) {
    const int cc = tid + 256 * it;
    vv[it] = *(const u16x4*)(Vb + (size_t)(cc >> 4) * 3072 + (cc & 15) * 4);
  }
  #pragma unroll
  for (int s = 0; s < 2; ++s) {
    const int c = s * 256 + tid;
    const int kv = c >> 3;
    const int dsrc = ((c & 7) * 8) ^ ((kv & 7) << 3);
    gload_lds16(Kb + (size_t)kv * 3072 + dsrc, &Ks[0][(size_t)(c & ~63) * 8]);
  }

  AttnState sA, sB;
  #pragma unroll
  for (int cb = 0; cb < 4; cb++) {
    sA.o[cb] = (f32x4){0.f, 0.f, 0.f, 0.f};
    sB.o[cb] = (f32x4){0.f, 0.f, 0.f, 0.f};
  }
  sA.m = -1e30f; sA.l = 0.f; sB.m = -1e30f; sB.l = 0.f;
  const int qgA = qA * 64 + wid * 16 + l15;
  const int qgB = qB * 64 + wid * 16 + l15;

  for (int kvb = 0; kvb <= qB; ++kvb) {
    const int cur = kvb & 1;
    const int kv0 = kvb * 64;
    __builtin_amdgcn_s_barrier();                 // #1: prev tile fully consumed
    asm volatile("s_waitcnt vmcnt(2)" ::: "memory");   // V(kvb) regs landed; K(kvb) flying
    #pragma unroll
    for (int it = 0; it < 4; ++it) {
      const int cc = tid + 256 * it;
      const int vkv = cc >> 4;
      const int vd = (cc & 15) * 4;
      #pragma unroll
      for (int j = 0; j < 4; j++) {
        const int d = vd + j;
        Vt[d * 64 + (vkv ^ (((d >> 2) & 7) << 3))] = vv[it][j];
      }
    }
    if (kvb < qB) {
      #pragma unroll
      for (int it = 0; it < 4; ++it) {
        const int cc = tid + 256 * it;
        vv[it] = *(const u16x4*)(Vb + (size_t)((kvb + 1) * 64 + (cc >> 4)) * 3072 + (cc & 15) * 4);
      }
      asm volatile("s_waitcnt vmcnt(4)" ::: "memory");  // K(kvb) landed; V(kvb+1) flying
    } else {
      asm volatile("s_waitcnt vmcnt(0)" ::: "memory");
    }
    asm volatile("s_waitcnt lgkmcnt(0)" ::: "memory");  // Vt ds_writes drained
    __builtin_amdgcn_s_barrier();                 // #2: Ks[cur], Vt published
    if (kvb < qB) {
      #pragma unroll
      for (int s = 0; s < 2; ++s) {
        const int c = s * 256 + tid;
        const int kv = c >> 3;
        const int dsrc = ((c & 7) * 8) ^ ((kv & 7) << 3);
        gload_lds16(Kb + (size_t)((kvb + 1) * 64 + kv) * 3072 + dsrc,
                    &Ks[cur ^ 1][(size_t)(c & ~63) * 8]);
      }
    }
    if (kvb <= qA)
      attn_tile(qfA, Ks[cur], Vt, Ps[0][wid], sA, kv0, qgA, l15, l4,
                kv0 + 63 > qA * 64 + wid * 16);
    attn_tile(qfB, Ks[cur], Vt, Ps[1][wid], sB, kv0, qgB, l15, l4,
              kv0 + 63 > qB * 64 + wid * 16);
  }
  attn_write(outb + ((size_t)b * 2048 + qA * 64 + wid * 16) * 1024 + h * 64, sA, l15, l4);
  attn_write(outb + ((size_t)b * 2048 + qB * 64 + wid * 16) * 1024 + h * 64, sB, l15, l4);
}

// ---------------- host ----------------
extern "C" void kernel_launch(void* const* d_in, const int* in_sizes, int n_in,
                              void* d_out, int out_size, void* d_ws, size_t ws_size,
                              hipStream_t stream) {
  const float* x      = (const float*)d_in[0];
  const float* ln1_g  = (const float*)d_in[1];
  const float* ln1_b  = (const float*)d_in[2];
  const float* qkv_w  = (const float*)d_in[3];
  const float* qkv_b  = (const float*)d_in[4];
  const float* proj_w = (const float*)d_in[5];
  const float* proj_b = (const float*)d_in[6];
  const float* ln2_g  = (const float*)d_in[7];
  const float* ln2_b  = (const float*)d_in[8];
  const float* ff1_w  = (const float*)d_in[9];
  const float* ff1_b  = (const float*)d_in[10];
  const float* ff2_w  = (const float*)d_in[11];
  const float* ff2_b  = (const float*)d_in[12];
  float* out = (float*)d_out;

  char* ws = (char*)d_ws;
  size_t off = 0;
  unsigned short* wbuf   = (unsigned short*)(ws + off); off += (size_t)4096 * 1024 * 2;  // 8 MiB
  unsigned short* hbuf   = (unsigned short*)(ws + off); off += (size_t)8192 * 1024 * 2;  // 16 MiB
  unsigned short* qkvbuf = (unsigned short*)(ws + off); off += (size_t)8192 * 3072 * 2;  // 48 MiB
  unsigned short* gbuf   = (unsigned short*)(ws + off);                                   // 64 MiB

  // ---- attention sublayer ----
  ln_kernel<<<8192, 256, 0, stream>>>(x, ln1_g, ln1_b, hbuf);
  transpose_kernel<<<dim3(3072 / 64, 1024 / 64), 256, 0, stream>>>(qkv_w, wbuf, 1024, 3072);
  gemm8_kernel<0><<<dim3(64 * 12), 512, 0, stream>>>(hbuf, wbuf, qkv_b, nullptr, qkvbuf,
                                                     8192, 3072, 1024);
  attn_kernel<<<dim3(16, 64), 256, 0, stream>>>(qkvbuf, hbuf);
  transpose_kernel<<<dim3(1024 / 64, 1024 / 64), 256, 0, stream>>>(proj_w, wbuf, 1024, 1024);
  gemm8_kernel<1><<<dim3(64 * 4), 512, 0, stream>>>(hbuf, wbuf, proj_b, x, out,
                                                    8192, 1024, 1024);   // x1 -> d_out (f32)
  // ---- MLP sublayer ----
  ln_kernel<<<8192, 256, 0, stream>>>(out, ln2_g, ln2_b, hbuf);
  transpose_kernel<<<dim3(4096 / 64, 1024 / 64), 256, 0, stream>>>(ff1_w, wbuf, 1024, 4096);
  gemm8_kernel<2><<<dim3(64 * 16), 512, 0, stream>>>(hbuf, wbuf, ff1_b, nullptr, gbuf,
                                                     8192, 4096, 1024);  // gelu
  transpose_kernel<<<dim3(1024 / 64, 4096 / 64), 256, 0, stream>>>(ff2_w, wbuf, 4096, 1024);
  gemm8_kernel<1><<<dim3(64 * 4), 512, 0, stream>>>(gbuf, wbuf, ff2_b, out, out,
                                                    8192, 1024, 4096);   // + x1 in-place
}